// Round 15
// baseline (375.036 us; speedup 1.0000x reference)
//
#include <hip/hip_runtime.h>

// Mamba3 SSM layer: B=2, L=2048, D_MODEL=1024, D_INNER=2048, D_STATE=32
#define DM   1024
#define DI   2048
#define DST  32
#define NB   2
#define LSEQ 2048
#define BL   (NB*LSEQ)   // 4096 rows
#define LC   32          // scan chunk length
#define NC   64          // number of chunks (LC*NC == LSEQ)

using bf16   = __bf16;
using bf16x4 = __attribute__((ext_vector_type(4))) __bf16;
using bf16x8 = __attribute__((ext_vector_type(8))) __bf16;
using f32x4  = __attribute__((ext_vector_type(4))) float;
using f16x2  = __attribute__((ext_vector_type(2))) _Float16;

#define AS1(p) ((const __attribute__((address_space(1))) void*)(p))
#define AS3(p) ((__attribute__((address_space(3))) void*)(p))

static __device__ __forceinline__ float sigmoidf_(float x) {
  return 1.f / (1.f + __expf(-x));
}

static __device__ __forceinline__ f16x2 pack_f16x2(float a, float b) {
  return __builtin_bit_cast(f16x2, __builtin_amdgcn_cvt_pkrtz(a, b));
}

static __device__ __forceinline__ float exp2_(float x) {
#if __has_builtin(__builtin_amdgcn_exp2f)
  return __builtin_amdgcn_exp2f(x);
#else
  return exp2f(x);
#endif
}

// ---------------- cast kernels ----------------
__global__ __launch_bounds__(256) void cast_bf16_kernel(
    const float* __restrict__ in, bf16* __restrict__ out, int n4) {
  int i = blockIdx.x * 256 + threadIdx.x;
  if (i >= n4) return;
  f32x4 v = ((const f32x4*)in)[i];
  bf16x4 o;
  #pragma unroll
  for (int j = 0; j < 4; ++j) o[j] = (bf16)v[j];
  ((bf16x4*)out)[i] = o;
}

// W_xproj (65,2048) -> bf16 padded+PERMUTED to (128,2048):
// out rows 0..31 = B rows (src 1..32), 32..63 = C rows (src 33..64),
// row 127 = dt_raw (src 0), rest zero.  => proj row: [B|C|pad|dtraw]
__global__ __launch_bounds__(256) void padcast_wxp_kernel(
    const float* __restrict__ in, bf16* __restrict__ out) {
  int i = blockIdx.x * 256 + threadIdx.x;   // over 128*2048/4 = 65536
  int k4 = i & 511;
  int r  = i >> 9;
  int src = (r < 64) ? (r + 1) : ((r == 127) ? 0 : -1);
  f32x4 v = {0.f, 0.f, 0.f, 0.f};
  if (src >= 0) v = *(const f32x4*)(in + (size_t)src * 2048 + k4 * 4);
  bf16x4 o;
  #pragma unroll
  for (int j = 0; j < 4; ++j) o[j] = (bf16)v[j];
  ((bf16x4*)out)[i] = o;
}

// gate precompute: g = silu(z) as f16, written into the dead x_in half of xz.
// g[bl][d] lives at ((f16*)xz)[bl*8192 + d] (first 4 KB of each 16 KB row).
__global__ __launch_bounds__(256) void zprep_kernel(
    const float* __restrict__ xz, _Float16* __restrict__ gs) {
  int i = blockIdx.x * 256 + threadIdx.x;   // over BL*DI/4 = 2,097,152
  int d4 = (i & 511) * 4;
  int bl = i >> 9;
  f32x4 z = *(const f32x4*)(xz + (size_t)bl * 4096 + 2048 + d4);
  float g0 = z[0] * sigmoidf_(z[0]);
  float g1 = z[1] * sigmoidf_(z[1]);
  float g2 = z[2] * sigmoidf_(z[2]);
  float g3 = z[3] * sigmoidf_(z[3]);
  uint2 o;
  o.x = __builtin_bit_cast(unsigned int, pack_f16x2(g0, g1));
  o.y = __builtin_bit_cast(unsigned int, pack_f16x2(g2, g3));
  *(uint2*)(gs + (size_t)bl * 8192 + d4) = o;
}

// ---------------- bf16 MFMA GEMM (m97 structure): C = A * B^T ----------------
// 128x128 tile, BK=32, linear LDS [ks][128][8] staged via global_load_lds x16.
// nz>1: K split into nz segments over blockIdx.z; Cz = C + z*M*N (partials).
__global__ __launch_bounds__(256) void gemm_lds(
    const bf16* __restrict__ A, const bf16* __restrict__ B,
    float* __restrict__ C, int M, int N, int K, int nz) {
  __shared__ bf16 As2[4][128][8];   // 8 KB
  __shared__ bf16 Bs2[4][128][8];   // 8 KB

  int tid  = threadIdx.x;
  int bm   = blockIdx.y, bn = blockIdx.x;
  int row0 = bm * 128, col0 = bn * 128;
  int w    = tid >> 6, lane = tid & 63;
  int wr   = w >> 1, wc = w & 1;
  int lr   = lane & 15, lk = lane >> 4;

  int seg = K / nz;
  int kb  = blockIdx.z * seg, ke = kb + seg;
  float* Cz = C + (size_t)blockIdx.z * ((size_t)M * N);

  f32x4 acc[4][4];
  #pragma unroll
  for (int i = 0; i < 4; ++i)
    #pragma unroll
    for (int j = 0; j < 4; ++j) acc[i][j] = f32x4{0.f, 0.f, 0.f, 0.f};

  // staging slots: instr i in {0,1}: j = i*256 + w*64 + lane; ks=j>>7, row=j&127
  int j0 = w * 64 + lane, j1 = 256 + w * 64 + lane;
  int ks0 = j0 >> 7, r0s = j0 & 127;
  int ks1 = j1 >> 7, r1s = j1 & 127;
  const bf16* Ag0 = A + (size_t)(row0 + r0s) * K + ks0 * 8;
  const bf16* Ag1 = A + (size_t)(row0 + r1s) * K + ks1 * 8;
  const bf16* Bg0 = B + (size_t)(col0 + r0s) * K + ks0 * 8;
  const bf16* Bg1 = B + (size_t)(col0 + r1s) * K + ks1 * 8;
  bf16* AsL = &As2[0][0][0];
  bf16* BsL = &Bs2[0][0][0];
  int base0 = (w * 64) * 8;          // shorts, wave-uniform
  int base1 = (256 + w * 64) * 8;

  for (int k0 = kb; k0 < ke; k0 += 32) {
    __builtin_amdgcn_global_load_lds(AS1(Ag0 + k0), AS3(AsL + base0), 16, 0, 0);
    __builtin_amdgcn_global_load_lds(AS1(Ag1 + k0), AS3(AsL + base1), 16, 0, 0);
    __builtin_amdgcn_global_load_lds(AS1(Bg0 + k0), AS3(BsL + base0), 16, 0, 0);
    __builtin_amdgcn_global_load_lds(AS1(Bg1 + k0), AS3(BsL + base1), 16, 0, 0);
    __syncthreads();

    bf16x8 af[4], bff[4];
    #pragma unroll
    for (int mi = 0; mi < 4; ++mi)
      af[mi] = *(const bf16x8*)&As2[lk][wr * 64 + mi * 16 + lr][0];
    #pragma unroll
    for (int ni = 0; ni < 4; ++ni)
      bff[ni] = *(const bf16x8*)&Bs2[lk][wc * 64 + ni * 16 + lr][0];

    #pragma unroll
    for (int mi = 0; mi < 4; ++mi)
      #pragma unroll
      for (int ni = 0; ni < 4; ++ni)
        acc[mi][ni] = __builtin_amdgcn_mfma_f32_16x16x32_bf16(
            af[mi], bff[ni], acc[mi][ni], 0, 0, 0);
    __syncthreads();
  }

  // C/D layout: col = lane&15, row = (lane>>4)*4 + reg
  #pragma unroll
  for (int mi = 0; mi < 4; ++mi)
    #pragma unroll
    for (int ni = 0; ni < 4; ++ni) {
      int r0 = row0 + wr * 64 + mi * 16 + lk * 4;
      int c  = col0 + wc * 64 + ni * 16 + lr;
      #pragma unroll
      for (int r = 0; r < 4; ++r)
        Cz[(size_t)(r0 + r) * N + c] = acc[mi][ni][r];
    }
}

// reduce 8 K-split partials -> proj
__global__ __launch_bounds__(256) void reduce_proj_kernel(
    const float* __restrict__ part, float* __restrict__ proj) {
  int i = blockIdx.x * 256 + threadIdx.x;   // over 4096*128/4 = 131072
  f32x4 s = ((const f32x4*)part)[i];
  #pragma unroll
  for (int z = 1; z < 8; ++z) s += ((const f32x4*)part)[(size_t)z * 131072 + i];
  ((f32x4*)proj)[i] = s;
}

// reduce 2 K-split partials -> out
__global__ __launch_bounds__(256) void reduce_out_kernel(
    const float* __restrict__ part, float* __restrict__ out) {
  int i = blockIdx.x * 256 + threadIdx.x;   // over 4096*1024/4 = 1,048,576
  f32x4 s = ((const f32x4*)part)[i];
  s += ((const f32x4*)part)[(size_t)1048576 + i];
  ((f32x4*)out)[i] = s;
}

// ---------------- depthwise conv3 + SiLU -> bf16 ----------------
__global__ __launch_bounds__(256) void conv_silu_kernel(
    const float* __restrict__ xz, bf16* __restrict__ xconv,
    const float* __restrict__ conv_w, const float* __restrict__ conv_b) {
  int i = blockIdx.x * 256 + threadIdx.x;  // over BL * DI/4
  int d4 = i & 511;
  int d  = d4 * 4;
  int bl = i >> 9;
  int l  = bl & (LSEQ - 1);

  const float* base = xz + (size_t)bl * (2 * DI) + d;
  f32x4 zero = {0.f, 0.f, 0.f, 0.f};
  f32x4 xm = (l > 0)        ? *(const f32x4*)(base - 2 * DI) : zero;
  f32x4 xc = *(const f32x4*)(base);
  f32x4 xp = (l < LSEQ - 1) ? *(const f32x4*)(base + 2 * DI) : zero;

  bf16x4 o;
  #pragma unroll
  for (int j = 0; j < 4; ++j) {
    float w0 = conv_w[(d + j) * 3 + 0];
    float w1 = conv_w[(d + j) * 3 + 1];
    float w2 = conv_w[(d + j) * 3 + 2];
    float v = fmaf(w0, xm[j], fmaf(w1, xc[j], fmaf(w2, xp[j], conv_b[d + j])));
    v = v * sigmoidf_(v);
    o[j] = (bf16)v;
  }
  *(bf16x4*)(xconv + (size_t)bl * DI + d) = o;
}

// ---------------- chunked SSM scan, d-major, 2-way n-split, LDS-staged -------
// lane = (d&31) + 32*nh; 16 states/thread. Block 256 = 4 waves covers d-range
// of 128 for one (b,c). All per-step operands (B, C, dtraw, u, g) staged in
// LDS via global_load_lds -> inner loop has ZERO global accesses.
// launch_bounds (256,6): 85-VGPR bin; state ~70 regs fits (unroll 2 only --
// r12's spill was unroll 4).

__global__ __launch_bounds__(256, 6) void scan_phase1(
    const float* __restrict__ proj, const bf16* __restrict__ xconv,
    const float* __restrict__ A_log, const float* __restrict__ W_dt,
    const float* __restrict__ b_dt, const float* __restrict__ alpha,
    unsigned int* __restrict__ PH) {
  __shared__ float Bs[LC][32];    // 4 KB: B values of the chunk
  __shared__ bf16  Us[LC][128];   // 8 KB: u values of the chunk
  __shared__ float Ds[LC];        // dtraw per step
  int tid = threadIdx.x;
  int wid = tid >> 6, lane = tid & 63;
  int dl = lane & 31, nh = lane >> 5;
  int di = wid * 32 + dl;              // d index within block's 128
  int d = blockIdx.x * 128 + di;
  int b = blockIdx.y, c = blockIdx.z;
  int n0 = nh * 16;

  const float* pb = proj + ((size_t)b * LSEQ + c * LC) * 128;
  const bf16*  ub = xconv + ((size_t)b * LSEQ + c * LC) * DI + blockIdx.x * 128;

  // stage B: slot s = tid (256 slots of 16B): row r=s>>3, quad q=s&7
  {
    const float* g = pb + (size_t)(tid >> 3) * 128 + (tid & 7) * 4;
    __builtin_amdgcn_global_load_lds(AS1(g), AS3((char*)&Bs[0][0] + wid * 1024),
                                     16, 0, 0);
  }
  // stage U: 512 slots of 16B (8 bf16): row s>>4, oct s&15
  #pragma unroll
  for (int k = 0; k < 2; ++k) {
    int s = k * 256 + wid * 64 + lane;
    const bf16* g = ub + (size_t)(s >> 4) * DI + (s & 15) * 8;
    __builtin_amdgcn_global_load_lds(AS1(g),
        AS3((char*)&Us[0][0] + (k * 256 + wid * 64) * 16), 16, 0, 0);
  }
  if (tid < LC) Ds[tid] = pb[(size_t)tid * 128 + 127];

  float aG = sigmoidf_(alpha[0]), omA = 1.f - aG;
  float Wd = W_dt[d], bd = b_dt[d];

  float Ar2[16];   // -exp(A_log)*log2(e)
  #pragma unroll
  for (int n = 0; n < 16; n += 4) {
    f32x4 al = *(const f32x4*)(A_log + (size_t)d * DST + n0 + n);
    #pragma unroll
    for (int j = 0; j < 4; ++j) Ar2[n + j] = -__expf(al[j]) * 1.44269504f;
  }

  float h[16], P[16];
  #pragma unroll
  for (int n = 0; n < 16; ++n) { h[n] = 0.f; P[n] = 1.f; }

  __syncthreads();

  #pragma unroll 2
  for (int t = 0; t < LC; ++t) {
    float dtraw = Ds[t];
    float u = (float)Us[t][di];
    float s = fmaf(dtraw, Wd, bd);
    float dt = (s > 15.f) ? s : __logf(1.f + __expf(s));  // softplus
    float dtu = dt * u;
    #pragma unroll
    for (int n4 = 0; n4 < 4; ++n4) {
      f32x4 Bq = *(const f32x4*)&Bs[t][((n0 + n4 * 4) & 31)];
      #pragma unroll
      for (int j = 0; j < 4; ++j) {
        int n = n4 * 4 + j;
        float t1  = dt * Ar2[n];                       // dtA*log2e
        float ex  = exp2_(t1);
        float den = fmaf(t1, -0.34657359f, 1.000001f); // 1 - 0.5*dtA + 1e-6
        float Ad  = fmaf(aG, ex, omA * __builtin_amdgcn_rcpf(den));
        P[n] *= Ad;
        h[n] = fmaf(Ad, h[n], dtu * Bq[j]);
      }
    }
  }
  size_t ob = (((size_t)c * NB + b) * DI + d) * DST + n0;
  #pragma unroll
  for (int n4 = 0; n4 < 4; ++n4) {
    uint4 o;
    #pragma unroll
    for (int j = 0; j < 4; ++j) {
      int n = n4 * 4 + j;
      ((unsigned int*)&o)[j] =
          __builtin_bit_cast(unsigned int, pack_f16x2(P[n], h[n]));
    }
    *(uint4*)(PH + ob + n4 * 4) = o;
  }
}

// thread per (b,d,n): serial combine over NC chunks; in-place packed->f32.
// (chunk NC-1's packed slot is never written by phase1 -- its value only
// affects the discarded final H.)
__global__ __launch_bounds__(256) void scan_phase2(unsigned int* __restrict__ PH) {
  int i = blockIdx.x * 256 + threadIdx.x;   // 0 .. NB*DI*DST-1 = 131071
  float H = 0.f;
  #pragma unroll 4
  for (int c = 0; c < NC; ++c) {
    size_t idx = (size_t)c * (NB * DI * DST) + i;
    f16x2 ph = __builtin_bit_cast(f16x2, PH[idx]);
    ((float*)PH)[idx] = H;                        // start state for chunk c
    H = fmaf((float)ph[0], H, (float)ph[1]);      // end state of chunk c
  }
}

// phase3: re-run chunk from true start state; LDS-staged B/C/dtraw/u/g.
__global__ __launch_bounds__(256, 6) void scan_phase3(
    const float* __restrict__ proj, const bf16* __restrict__ xconv,
    const _Float16* __restrict__ gsrc,  // silu(z) f16, rows of 8192
    const float* __restrict__ A_log, const float* __restrict__ D_skip,
    const float* __restrict__ W_dt, const float* __restrict__ b_dt,
    const float* __restrict__ alpha, const float* __restrict__ PH,
    bf16* __restrict__ yb) {
  __shared__ float    BCs[LC][64];  // 8 KB: B|C values of the chunk
  __shared__ bf16     Us[LC][128];  // 8 KB: u values
  __shared__ _Float16 Gs[LC][128];  // 8 KB: gate values
  __shared__ float    Ds[LC];       // dtraw per step
  int tid = threadIdx.x;
  int wid = tid >> 6, lane = tid & 63;
  int dl = lane & 31, nh = lane >> 5;
  int di = wid * 32 + dl;
  int d = blockIdx.x * 128 + di;
  int b = blockIdx.y, c = blockIdx.z;
  int n0 = nh * 16;

  const float* pb = proj + ((size_t)b * LSEQ + c * LC) * 128;
  const bf16*  ub = xconv + ((size_t)b * LSEQ + c * LC) * DI + blockIdx.x * 128;
  const _Float16* gb = gsrc + ((size_t)b * LSEQ + c * LC) * 8192
                       + blockIdx.x * 128;

  // stage B|C: slots s = tid, tid+256 (512 slots): row s>>4, quad s&15
  {
    const float* g0 = pb + (size_t)(tid >> 4) * 128 + (tid & 15) * 4;
    int s1 = tid + 256;
    const float* g1 = pb + (size_t)(s1 >> 4) * 128 + (s1 & 15) * 4;
    char* base = (char*)&BCs[0][0];
    __builtin_amdgcn_global_load_lds(AS1(g0), AS3(base + wid * 1024), 16, 0, 0);
    __builtin_amdgcn_global_load_lds(AS1(g1), AS3(base + 4096 + wid * 1024),
                                     16, 0, 0);
  }
  // stage U: 512 slots of 16B: row s>>4, oct s&15
  #pragma unroll
  for (int k = 0; k < 2; ++k) {
    int s = k * 256 + wid * 64 + lane;
    const bf16* g = ub + (size_t)(s >> 4) * DI + (s & 15) * 8;
    __builtin_amdgcn_global_load_lds(AS1(g),
        AS3((char*)&Us[0][0] + (k * 256 + wid * 64) * 16), 16, 0, 0);
  }
  // stage G: 512 slots of 16B (8 f16): row s>>4 (stride 8192 f16), oct s&15
  #pragma unroll
  for (int k = 0; k < 2; ++k) {
    int s = k * 256 + wid * 64 + lane;
    const _Float16* g = gb + (size_t)(s >> 4) * 8192 + (s & 15) * 8;
    __builtin_amdgcn_global_load_lds(AS1(g),
        AS3((char*)&Gs[0][0] + (k * 256 + wid * 64) * 16), 16, 0, 0);
  }
  if (tid < LC) Ds[tid] = pb[(size_t)tid * 128 + 127];

  float aG = sigmoidf_(alpha[0]), omA = 1.f - aG;
  float Dsk = D_skip[d];
  float Wd = W_dt[d], bd = b_dt[d];

  float Ar2[16];
  #pragma unroll
  for (int n = 0; n < 16; n += 4) {
    f32x4 al = *(const f32x4*)(A_log + (size_t)d * DST + n0 + n);
    #pragma unroll
    for (int j = 0; j < 4; ++j) Ar2[n + j] = -__expf(al[j]) * 1.44269504f;
  }

  float h[16];
  size_t ob = (((size_t)c * NB + b) * DI + d) * DST + n0;
  #pragma unroll
  for (int n = 0; n < 16; n += 4) {
    f32x4 hv = *(const f32x4*)(PH + ob + n);
    #pragma unroll
    for (int j = 0; j < 4; ++j) h[n + j] = hv[j];
  }

  bf16* yc = yb + ((size_t)b * LSEQ + c * LC) * DI + d;

  __syncthreads();

  #pragma unroll 2
  for (int t = 0; t < LC; ++t) {
    float dtraw = Ds[t];
    float u = (float)Us[t][di];
    float s = fmaf(dtraw, Wd, bd);
    float dt = (s > 15.f) ? s : __logf(1.f + __expf(s));  // softplus
    float dtu = dt * u;
    float p0 = 0.f, p1 = 0.f, p2 = 0.f, p3 = 0.f;
    #pragma unroll
    for (int n4 = 0; n4 < 4; ++n4) {
      f32x4 Bq = *(const f32x4*)&BCs[t][n0 + n4 * 4];
      f32x4 Cq = *(const f32x4*)&BCs[t][32 + n0 + n4 * 4];
      #pragma unroll
      for (int j = 0; j < 4; ++j) {
        int n = n4 * 4 + j;
        float t1  = dt * Ar2[n];
        float ex  = exp2_(t1);
        float den = fmaf(t1, -0.34657359f, 1.000001f);
        float Ad  = fmaf(aG, ex, omA * __builtin_amdgcn_rcpf(den));
        h[n] = fmaf(Ad, h[n], dtu * Bq[j]);
        if (j == 0)      p0 = fmaf(Cq[j], h[n], p0);
        else if (j == 1) p1 = fmaf(Cq[j], h[n], p1);
        else if (j == 2) p2 = fmaf(Cq[j], h[n], p2);
        else             p3 = fmaf(Cq[j], h[n], p3);
      }
    }
    float part = (p0 + p1) + (p2 + p3);
    part += __shfl_xor(part, 32);   // combine the two 16-state halves
    if (nh == 0) {
      float g = (float)Gs[t][di];
      float y = fmaf(Dsk, u, part) * g;
      yc[(size_t)t * DI] = (bf16)y;
    }
  }
}

// ---------------- launch ----------------
extern "C" void kernel_launch(void* const* d_in, const int* in_sizes, int n_in,
                              void* d_out, int out_size, void* d_ws, size_t ws_size,
                              hipStream_t stream) {
  const float* x      = (const float*)d_in[0];
  const float* W_in   = (const float*)d_in[1];
  const float* conv_w = (const float*)d_in[2];
  const float* conv_b = (const float*)d_in[3];
  const float* A_log  = (const float*)d_in[4];
  const float* D_skip = (const float*)d_in[5];
  const float* W_xprj = (const float*)d_in[6];
  const float* W_dt   = (const float*)d_in[7];
  const float* b_dt   = (const float*)d_in[8];
  const float* alpha  = (const float*)d_in[9];
  const float* W_out  = (const float*)d_in[10];

  char* ws = (char*)d_ws;
  // Layout (141,033,472 B total — proven size):
  float* xz    = (float*)(ws + 0);             // (4096,4096) f32: 67,108,864
  bf16*  xconv = (bf16*) (ws + 67108864);      // (4096,2048) bf16: 16,777,216
  float* proj  = (float*)(ws + 83886080);      // (4096,128)  f32:   2,097,152
  bf16*  woutb = (bf16*) (ws + 85983232);      // (1024,2048) bf16:  4,194,304
  bf16*  wxpb  = (bf16*) (ws + 90177536);      // (128,2048)  bf16:    524,288
  bf16*  yb    = (bf16*) (ws + 90701824);      // (4096,2048) bf16: 16,777,216
  unsigned int* PH = (unsigned int*)(ws + 107479040);  // NC*NB*DI*DST u32: 33,554,432
  // overlays of the PH region (all dead before phase1 writes PH):
  bf16*  xb    = (bf16*) (ws + 107479040);     // (4096,1024) bf16: 8,388,608 (dead after GEMM1)
  bf16*  winb  = (bf16*) (ws + 115867648);     // (4096,1024) bf16: 8,388,608 (dead after GEMM1)
  float* projp = (float*)(ws + 107479040);     // 8x(4096,128) f32: 16,777,216 (dead after reduce)
  // after phase3, PH is dead again -> GEMM3 partials (2x4096x1024 f32 = 33.5 MB)
  float* outp  = (float*)(ws + 107479040);
  // gate f16 buffer overlays the dead x_in half of xz (first 4 KB of each row)
  _Float16* gs = (_Float16*)xz;

  float* out = (float*)d_out;  // (4096, 1024) f32

  // casts
  cast_bf16_kernel<<<4096, 256, 0, stream>>>(x, xb, BL * DM / 4);
  cast_bf16_kernel<<<4096, 256, 0, stream>>>(W_in, winb, 2 * DI * DM / 4);
  cast_bf16_kernel<<<2048, 256, 0, stream>>>(W_out, woutb, DM * DI / 4);
  padcast_wxp_kernel<<<256, 256, 0, stream>>>(W_xprj, wxpb);

  // xz = x @ W_in.T   (M=4096, N=4096, K=1024)
  gemm_lds<<<dim3(32, 32, 1), 256, 0, stream>>>(xb, winb, xz, BL, 2 * DI, DM, 1);

  // x_conv = silu(conv1d(x_in))
  conv_silu_kernel<<<8192, 256, 0, stream>>>(xz, xconv, conv_w, conv_b);

  // gate precompute (overwrites dead x_in half of xz)
  zprep_kernel<<<8192, 256, 0, stream>>>(xz, gs);

  // proj partials = x_conv @ W_xproj.T, K split 8-way; then reduce
  gemm_lds<<<dim3(1, 32, 8), 256, 0, stream>>>(xconv, wxpb, projp, BL, 128, DI, 8);
  reduce_proj_kernel<<<512, 256, 0, stream>>>(projp, proj);

  // chunked scan (d-major, 2-way n-split, fully LDS-staged operands)
  scan_phase1<<<dim3(DI / 128, NB, NC - 1), 256, 0, stream>>>(proj, xconv,
                                                              A_log, W_dt,
                                                              b_dt, alpha, PH);
  scan_phase2<<<512, 256, 0, stream>>>(PH);
  scan_phase3<<<dim3(DI / 128, NB, NC), 256, 0, stream>>>(proj, xconv, gs,
                                                          A_log, D_skip, W_dt,
                                                          b_dt, alpha,
                                                          (const float*)PH, yb);

  // out = y @ W_out.T (M=4096, N=1024, K=2048), K split 2-way into dead PH
  gemm_lds<<<dim3(8, 32, 2), 256, 0, stream>>>(yb, woutb, outp, BL, DM, DI, 2);
  reduce_out_kernel<<<4096, 256, 0, stream>>>(outp, out);
}

// Round 16
// 363.145 us; speedup vs baseline: 1.0327x; 1.0327x over previous
//
#include <hip/hip_runtime.h>

// Mamba3 SSM layer: B=2, L=2048, D_MODEL=1024, D_INNER=2048, D_STATE=32
#define DM   1024
#define DI   2048
#define DST  32
#define NB   2
#define LSEQ 2048
#define BL   (NB*LSEQ)   // 4096 rows
#define LC   32          // scan chunk length
#define NC   64          // number of chunks (LC*NC == LSEQ)

using bf16   = __bf16;
using bf16x4 = __attribute__((ext_vector_type(4))) __bf16;
using bf16x8 = __attribute__((ext_vector_type(8))) __bf16;
using f32x4  = __attribute__((ext_vector_type(4))) float;
using f16x2  = __attribute__((ext_vector_type(2))) _Float16;

#define AS1(p) ((const __attribute__((address_space(1))) void*)(p))
#define AS3(p) ((__attribute__((address_space(3))) void*)(p))

static __device__ __forceinline__ float sigmoidf_(float x) {
  return 1.f / (1.f + __expf(-x));
}

static __device__ __forceinline__ f16x2 pack_f16x2(float a, float b) {
  return __builtin_bit_cast(f16x2, __builtin_amdgcn_cvt_pkrtz(a, b));
}

static __device__ __forceinline__ float exp2_(float x) {
#if __has_builtin(__builtin_amdgcn_exp2f)
  return __builtin_amdgcn_exp2f(x);
#else
  return exp2f(x);
#endif
}

// ---------------- cast kernels ----------------
__global__ __launch_bounds__(256) void cast_bf16_kernel(
    const float* __restrict__ in, bf16* __restrict__ out, int n4) {
  int i = blockIdx.x * 256 + threadIdx.x;
  if (i >= n4) return;
  f32x4 v = ((const f32x4*)in)[i];
  bf16x4 o;
  #pragma unroll
  for (int j = 0; j < 4; ++j) o[j] = (bf16)v[j];
  ((bf16x4*)out)[i] = o;
}

// W_xproj (65,2048) -> bf16 padded+PERMUTED to (128,2048):
// out rows 0..31 = B rows (src 1..32), 32..63 = C rows (src 33..64),
// row 127 = dt_raw (src 0), rest zero.  => proj row: [B|C|pad|dtraw]
__global__ __launch_bounds__(256) void padcast_wxp_kernel(
    const float* __restrict__ in, bf16* __restrict__ out) {
  int i = blockIdx.x * 256 + threadIdx.x;   // over 128*2048/4 = 65536
  int k4 = i & 511;
  int r  = i >> 9;
  int src = (r < 64) ? (r + 1) : ((r == 127) ? 0 : -1);
  f32x4 v = {0.f, 0.f, 0.f, 0.f};
  if (src >= 0) v = *(const f32x4*)(in + (size_t)src * 2048 + k4 * 4);
  bf16x4 o;
  #pragma unroll
  for (int j = 0; j < 4; ++j) o[j] = (bf16)v[j];
  ((bf16x4*)out)[i] = o;
}

// ---------------- bf16 MFMA GEMM (m97 structure): C = A * B^T ----------------
// 128x128 tile, BK=32, linear LDS [ks][128][8] staged via global_load_lds x16.
// nz>1: K split into nz segments over blockIdx.z; Cz = C + z*M*N (partials).
__global__ __launch_bounds__(256) void gemm_lds(
    const bf16* __restrict__ A, const bf16* __restrict__ B,
    float* __restrict__ C, int M, int N, int K, int nz) {
  __shared__ bf16 As2[4][128][8];   // 8 KB
  __shared__ bf16 Bs2[4][128][8];   // 8 KB

  int tid  = threadIdx.x;
  int bm   = blockIdx.y, bn = blockIdx.x;
  int row0 = bm * 128, col0 = bn * 128;
  int w    = tid >> 6, lane = tid & 63;
  int wr   = w >> 1, wc = w & 1;
  int lr   = lane & 15, lk = lane >> 4;

  int seg = K / nz;
  int kb  = blockIdx.z * seg, ke = kb + seg;
  float* Cz = C + (size_t)blockIdx.z * ((size_t)M * N);

  f32x4 acc[4][4];
  #pragma unroll
  for (int i = 0; i < 4; ++i)
    #pragma unroll
    for (int j = 0; j < 4; ++j) acc[i][j] = f32x4{0.f, 0.f, 0.f, 0.f};

  // staging slots: instr i in {0,1}: j = i*256 + w*64 + lane; ks=j>>7, row=j&127
  int j0 = w * 64 + lane, j1 = 256 + w * 64 + lane;
  int ks0 = j0 >> 7, r0s = j0 & 127;
  int ks1 = j1 >> 7, r1s = j1 & 127;
  const bf16* Ag0 = A + (size_t)(row0 + r0s) * K + ks0 * 8;
  const bf16* Ag1 = A + (size_t)(row0 + r1s) * K + ks1 * 8;
  const bf16* Bg0 = B + (size_t)(col0 + r0s) * K + ks0 * 8;
  const bf16* Bg1 = B + (size_t)(col0 + r1s) * K + ks1 * 8;
  bf16* AsL = &As2[0][0][0];
  bf16* BsL = &Bs2[0][0][0];
  int base0 = (w * 64) * 8;          // shorts, wave-uniform
  int base1 = (256 + w * 64) * 8;

  for (int k0 = kb; k0 < ke; k0 += 32) {
    __builtin_amdgcn_global_load_lds(AS1(Ag0 + k0), AS3(AsL + base0), 16, 0, 0);
    __builtin_amdgcn_global_load_lds(AS1(Ag1 + k0), AS3(AsL + base1), 16, 0, 0);
    __builtin_amdgcn_global_load_lds(AS1(Bg0 + k0), AS3(BsL + base0), 16, 0, 0);
    __builtin_amdgcn_global_load_lds(AS1(Bg1 + k0), AS3(BsL + base1), 16, 0, 0);
    __syncthreads();

    bf16x8 af[4], bff[4];
    #pragma unroll
    for (int mi = 0; mi < 4; ++mi)
      af[mi] = *(const bf16x8*)&As2[lk][wr * 64 + mi * 16 + lr][0];
    #pragma unroll
    for (int ni = 0; ni < 4; ++ni)
      bff[ni] = *(const bf16x8*)&Bs2[lk][wc * 64 + ni * 16 + lr][0];

    #pragma unroll
    for (int mi = 0; mi < 4; ++mi)
      #pragma unroll
      for (int ni = 0; ni < 4; ++ni)
        acc[mi][ni] = __builtin_amdgcn_mfma_f32_16x16x32_bf16(
            af[mi], bff[ni], acc[mi][ni], 0, 0, 0);
    __syncthreads();
  }

  // C/D layout: col = lane&15, row = (lane>>4)*4 + reg
  #pragma unroll
  for (int mi = 0; mi < 4; ++mi)
    #pragma unroll
    for (int ni = 0; ni < 4; ++ni) {
      int r0 = row0 + wr * 64 + mi * 16 + lk * 4;
      int c  = col0 + wc * 64 + ni * 16 + lr;
      #pragma unroll
      for (int r = 0; r < 4; ++r)
        Cz[(size_t)(r0 + r) * N + c] = acc[mi][ni][r];
    }
}

// reduce 8 K-split partials -> proj
__global__ __launch_bounds__(256) void reduce_proj_kernel(
    const float* __restrict__ part, float* __restrict__ proj) {
  int i = blockIdx.x * 256 + threadIdx.x;   // over 4096*128/4 = 131072
  f32x4 s = ((const f32x4*)part)[i];
  #pragma unroll
  for (int z = 1; z < 8; ++z) s += ((const f32x4*)part)[(size_t)z * 131072 + i];
  ((f32x4*)proj)[i] = s;
}

// reduce 2 K-split partials -> out
__global__ __launch_bounds__(256) void reduce_out_kernel(
    const float* __restrict__ part, float* __restrict__ out) {
  int i = blockIdx.x * 256 + threadIdx.x;   // over 4096*1024/4 = 1,048,576
  f32x4 s = ((const f32x4*)part)[i];
  s += ((const f32x4*)part)[(size_t)1048576 + i];
  ((f32x4*)out)[i] = s;
}

// ---------------- depthwise conv3 + SiLU -> bf16 ----------------
__global__ __launch_bounds__(256) void conv_silu_kernel(
    const float* __restrict__ xz, bf16* __restrict__ xconv,
    const float* __restrict__ conv_w, const float* __restrict__ conv_b) {
  int i = blockIdx.x * 256 + threadIdx.x;  // over BL * DI/4
  int d4 = i & 511;
  int d  = d4 * 4;
  int bl = i >> 9;
  int l  = bl & (LSEQ - 1);

  const float* base = xz + (size_t)bl * (2 * DI) + d;
  f32x4 zero = {0.f, 0.f, 0.f, 0.f};
  f32x4 xm = (l > 0)        ? *(const f32x4*)(base - 2 * DI) : zero;
  f32x4 xc = *(const f32x4*)(base);
  f32x4 xp = (l < LSEQ - 1) ? *(const f32x4*)(base + 2 * DI) : zero;

  bf16x4 o;
  #pragma unroll
  for (int j = 0; j < 4; ++j) {
    float w0 = conv_w[(d + j) * 3 + 0];
    float w1 = conv_w[(d + j) * 3 + 1];
    float w2 = conv_w[(d + j) * 3 + 2];
    float v = fmaf(w0, xm[j], fmaf(w1, xc[j], fmaf(w2, xp[j], conv_b[d + j])));
    v = v * sigmoidf_(v);
    o[j] = (bf16)v;
  }
  *(bf16x4*)(xconv + (size_t)bl * DI + d) = o;
}

// ---------------- chunked SSM scan, d-major, 2-way n-split, LDS-staged -------
// lane = (d&31) + 32*nh; 16 states/thread. Block 256 = 4 waves covers d-range
// of 128 for one (b,c). All per-step operands (B, C, dtraw, u, g) staged in
// LDS -> inner loop has ZERO global accesses.

// phase1: launch_bounds (256,4) -- r14 proven (r12/r15 lesson: this kernel
// spills or degrades at tighter caps).
__global__ __launch_bounds__(256, 4) void scan_phase1(
    const float* __restrict__ proj, const bf16* __restrict__ xconv,
    const float* __restrict__ A_log, const float* __restrict__ W_dt,
    const float* __restrict__ b_dt, const float* __restrict__ alpha,
    unsigned int* __restrict__ PH) {
  __shared__ float Bs[LC][32];    // 4 KB: B values of the chunk
  __shared__ bf16  Us[LC][128];   // 8 KB: u values of the chunk
  __shared__ float Ds[LC];        // dtraw per step
  int tid = threadIdx.x;
  int wid = tid >> 6, lane = tid & 63;
  int dl = lane & 31, nh = lane >> 5;
  int di = wid * 32 + dl;              // d index within block's 128
  int d = blockIdx.x * 128 + di;
  int b = blockIdx.y, c = blockIdx.z;
  int n0 = nh * 16;

  const float* pb = proj + ((size_t)b * LSEQ + c * LC) * 128;
  const bf16*  ub = xconv + ((size_t)b * LSEQ + c * LC) * DI + blockIdx.x * 128;

  // stage B: slot s = tid (256 slots of 16B): row r=s>>3, quad q=s&7
  {
    const float* g = pb + (size_t)(tid >> 3) * 128 + (tid & 7) * 4;
    __builtin_amdgcn_global_load_lds(AS1(g), AS3((char*)&Bs[0][0] + wid * 1024),
                                     16, 0, 0);
  }
  // stage U: 512 slots of 16B (8 bf16): row s>>4, oct s&15
  #pragma unroll
  for (int k = 0; k < 2; ++k) {
    int s = k * 256 + wid * 64 + lane;
    const bf16* g = ub + (size_t)(s >> 4) * DI + (s & 15) * 8;
    __builtin_amdgcn_global_load_lds(AS1(g),
        AS3((char*)&Us[0][0] + (k * 256 + wid * 64) * 16), 16, 0, 0);
  }
  if (tid < LC) Ds[tid] = pb[(size_t)tid * 128 + 127];

  float aG = sigmoidf_(alpha[0]), omA = 1.f - aG;
  float Wd = W_dt[d], bd = b_dt[d];

  float Ar2[16];   // -exp(A_log)*log2(e)
  #pragma unroll
  for (int n = 0; n < 16; n += 4) {
    f32x4 al = *(const f32x4*)(A_log + (size_t)d * DST + n0 + n);
    #pragma unroll
    for (int j = 0; j < 4; ++j) Ar2[n + j] = -__expf(al[j]) * 1.44269504f;
  }

  float h[16], P[16];
  #pragma unroll
  for (int n = 0; n < 16; ++n) { h[n] = 0.f; P[n] = 1.f; }

  __syncthreads();

  #pragma unroll 2
  for (int t = 0; t < LC; ++t) {
    float dtraw = Ds[t];
    float u = (float)Us[t][di];
    float s = fmaf(dtraw, Wd, bd);
    float dt = (s > 15.f) ? s : __logf(1.f + __expf(s));  // softplus
    float dtu = dt * u;
    #pragma unroll
    for (int n4 = 0; n4 < 4; ++n4) {
      f32x4 Bq = *(const f32x4*)&Bs[t][((n0 + n4 * 4) & 31)];
      #pragma unroll
      for (int j = 0; j < 4; ++j) {
        int n = n4 * 4 + j;
        float t1  = dt * Ar2[n];                       // dtA*log2e
        float ex  = exp2_(t1);
        float den = fmaf(t1, -0.34657359f, 1.000001f); // 1 - 0.5*dtA + 1e-6
        float Ad  = fmaf(aG, ex, omA * __builtin_amdgcn_rcpf(den));
        P[n] *= Ad;
        h[n] = fmaf(Ad, h[n], dtu * Bq[j]);
      }
    }
  }
  size_t ob = (((size_t)c * NB + b) * DI + d) * DST + n0;
  #pragma unroll
  for (int n4 = 0; n4 < 4; ++n4) {
    uint4 o;
    #pragma unroll
    for (int j = 0; j < 4; ++j) {
      int n = n4 * 4 + j;
      ((unsigned int*)&o)[j] =
          __builtin_bit_cast(unsigned int, pack_f16x2(P[n], h[n]));
    }
    *(uint4*)(PH + ob + n4 * 4) = o;
  }
}

// thread per (b,d,n): serial combine over NC chunks; in-place packed->f32.
// (chunk NC-1's packed slot is never written by phase1 -- its value only
// affects the discarded final H.)
__global__ __launch_bounds__(256) void scan_phase2(unsigned int* __restrict__ PH) {
  int i = blockIdx.x * 256 + threadIdx.x;   // 0 .. NB*DI*DST-1 = 131071
  float H = 0.f;
  #pragma unroll 4
  for (int c = 0; c < NC; ++c) {
    size_t idx = (size_t)c * (NB * DI * DST) + i;
    f16x2 ph = __builtin_bit_cast(f16x2, PH[idx]);
    ((float*)PH)[idx] = H;                        // start state for chunk c
    H = fmaf((float)ph[0], H, (float)ph[1]);      // end state of chunk c
  }
}

// phase3: re-run chunk from true start state; LDS-staged B/C/dtraw/u/g.
// g = silu(z) converted to f16 DURING staging (reg-staged: z-half of xz is
// read-only here, so no WAR race; keeps LDS at 25 KB for occupancy).
__global__ __launch_bounds__(256, 6) void scan_phase3(
    const float* __restrict__ proj, const bf16* __restrict__ xconv,
    const float* __restrict__ xzf,   // z at col 2048+d
    const float* __restrict__ A_log, const float* __restrict__ D_skip,
    const float* __restrict__ W_dt, const float* __restrict__ b_dt,
    const float* __restrict__ alpha, const float* __restrict__ PH,
    bf16* __restrict__ yb) {
  __shared__ float    BCs[LC][64];  // 8 KB: B|C values of the chunk
  __shared__ bf16     Us[LC][128];  // 8 KB: u values
  __shared__ _Float16 Gs[LC][128];  // 8 KB: silu(z) values
  __shared__ float    Ds[LC];       // dtraw per step
  int tid = threadIdx.x;
  int wid = tid >> 6, lane = tid & 63;
  int dl = lane & 31, nh = lane >> 5;
  int di = wid * 32 + dl;
  int d = blockIdx.x * 128 + di;
  int b = blockIdx.y, c = blockIdx.z;
  int n0 = nh * 16;

  const float* pb = proj + ((size_t)b * LSEQ + c * LC) * 128;
  const bf16*  ub = xconv + ((size_t)b * LSEQ + c * LC) * DI + blockIdx.x * 128;
  const float* zb = xzf + ((size_t)b * LSEQ + c * LC) * 4096 + 2048
                    + blockIdx.x * 128;

  // stage B|C: slots s = tid, tid+256 (512 slots): row s>>4, quad s&15
  {
    const float* g0 = pb + (size_t)(tid >> 4) * 128 + (tid & 15) * 4;
    int s1 = tid + 256;
    const float* g1 = pb + (size_t)(s1 >> 4) * 128 + (s1 & 15) * 4;
    char* base = (char*)&BCs[0][0];
    __builtin_amdgcn_global_load_lds(AS1(g0), AS3(base + wid * 1024), 16, 0, 0);
    __builtin_amdgcn_global_load_lds(AS1(g1), AS3(base + 4096 + wid * 1024),
                                     16, 0, 0);
  }
  // stage U: 512 slots of 16B: row s>>4, oct s&15
  #pragma unroll
  for (int k = 0; k < 2; ++k) {
    int s = k * 256 + wid * 64 + lane;
    const bf16* g = ub + (size_t)(s >> 4) * DI + (s & 15) * 8;
    __builtin_amdgcn_global_load_lds(AS1(g),
        AS3((char*)&Us[0][0] + (k * 256 + wid * 64) * 16), 16, 0, 0);
  }
  // stage G: 1024 f32x4 slots -> silu -> f16, reg-staged (4 slots/thread)
  #pragma unroll
  for (int k = 0; k < 4; ++k) {
    int s = k * 256 + tid;
    int row = s >> 5, q = s & 31;
    f32x4 z = *(const f32x4*)(zb + (size_t)row * 4096 + q * 4);
    uint2 o;
    o.x = __builtin_bit_cast(unsigned int,
          pack_f16x2(z[0] * sigmoidf_(z[0]), z[1] * sigmoidf_(z[1])));
    o.y = __builtin_bit_cast(unsigned int,
          pack_f16x2(z[2] * sigmoidf_(z[2]), z[3] * sigmoidf_(z[3])));
    *(uint2*)&Gs[row][q * 4] = o;
  }
  if (tid < LC) Ds[tid] = pb[(size_t)tid * 128 + 127];

  float aG = sigmoidf_(alpha[0]), omA = 1.f - aG;
  float Dsk = D_skip[d];
  float Wd = W_dt[d], bd = b_dt[d];

  float Ar2[16];
  #pragma unroll
  for (int n = 0; n < 16; n += 4) {
    f32x4 al = *(const f32x4*)(A_log + (size_t)d * DST + n0 + n);
    #pragma unroll
    for (int j = 0; j < 4; ++j) Ar2[n + j] = -__expf(al[j]) * 1.44269504f;
  }

  float h[16];
  size_t ob = (((size_t)c * NB + b) * DI + d) * DST + n0;
  #pragma unroll
  for (int n = 0; n < 16; n += 4) {
    f32x4 hv = *(const f32x4*)(PH + ob + n);
    #pragma unroll
    for (int j = 0; j < 4; ++j) h[n + j] = hv[j];
  }

  bf16* yc = yb + ((size_t)b * LSEQ + c * LC) * DI + d;

  __syncthreads();

  #pragma unroll 2
  for (int t = 0; t < LC; ++t) {
    float dtraw = Ds[t];
    float u = (float)Us[t][di];
    float s = fmaf(dtraw, Wd, bd);
    float dt = (s > 15.f) ? s : __logf(1.f + __expf(s));  // softplus
    float dtu = dt * u;
    float p0 = 0.f, p1 = 0.f, p2 = 0.f, p3 = 0.f;
    #pragma unroll
    for (int n4 = 0; n4 < 4; ++n4) {
      f32x4 Bq = *(const f32x4*)&BCs[t][n0 + n4 * 4];
      f32x4 Cq = *(const f32x4*)&BCs[t][32 + n0 + n4 * 4];
      #pragma unroll
      for (int j = 0; j < 4; ++j) {
        int n = n4 * 4 + j;
        float t1  = dt * Ar2[n];
        float ex  = exp2_(t1);
        float den = fmaf(t1, -0.34657359f, 1.000001f);
        float Ad  = fmaf(aG, ex, omA * __builtin_amdgcn_rcpf(den));
        h[n] = fmaf(Ad, h[n], dtu * Bq[j]);
        if (j == 0)      p0 = fmaf(Cq[j], h[n], p0);
        else if (j == 1) p1 = fmaf(Cq[j], h[n], p1);
        else if (j == 2) p2 = fmaf(Cq[j], h[n], p2);
        else             p3 = fmaf(Cq[j], h[n], p3);
      }
    }
    float part = (p0 + p1) + (p2 + p3);
    part += __shfl_xor(part, 32);   // combine the two 16-state halves
    if (nh == 0) {
      float g = (float)Gs[t][di];
      float y = fmaf(Dsk, u, part) * g;
      yc[(size_t)t * DI] = (bf16)y;
    }
  }
}

// ---------------- launch ----------------
extern "C" void kernel_launch(void* const* d_in, const int* in_sizes, int n_in,
                              void* d_out, int out_size, void* d_ws, size_t ws_size,
                              hipStream_t stream) {
  const float* x      = (const float*)d_in[0];
  const float* W_in   = (const float*)d_in[1];
  const float* conv_w = (const float*)d_in[2];
  const float* conv_b = (const float*)d_in[3];
  const float* A_log  = (const float*)d_in[4];
  const float* D_skip = (const float*)d_in[5];
  const float* W_xprj = (const float*)d_in[6];
  const float* W_dt   = (const float*)d_in[7];
  const float* b_dt   = (const float*)d_in[8];
  const float* alpha  = (const float*)d_in[9];
  const float* W_out  = (const float*)d_in[10];

  char* ws = (char*)d_ws;
  // Layout (141,033,472 B total — proven size):
  float* xz    = (float*)(ws + 0);             // (4096,4096) f32: 67,108,864
  bf16*  xconv = (bf16*) (ws + 67108864);      // (4096,2048) bf16: 16,777,216
  float* proj  = (float*)(ws + 83886080);      // (4096,128)  f32:   2,097,152
  bf16*  woutb = (bf16*) (ws + 85983232);      // (1024,2048) bf16:  4,194,304
  bf16*  wxpb  = (bf16*) (ws + 90177536);      // (128,2048)  bf16:    524,288
  bf16*  yb    = (bf16*) (ws + 90701824);      // (4096,2048) bf16: 16,777,216
  unsigned int* PH = (unsigned int*)(ws + 107479040);  // NC*NB*DI*DST u32: 33,554,432
  // overlays of the PH region (all dead before phase1 writes PH):
  bf16*  xb    = (bf16*) (ws + 107479040);     // (4096,1024) bf16: 8,388,608 (dead after GEMM1)
  bf16*  winb  = (bf16*) (ws + 115867648);     // (4096,1024) bf16: 8,388,608 (dead after GEMM1)
  float* projp = (float*)(ws + 107479040);     // 8x(4096,128) f32: 16,777,216 (dead after reduce)
  // after phase3, PH is dead again -> GEMM3 partials (2x4096x1024 f32 = 33.5 MB)
  float* outp  = (float*)(ws + 107479040);

  float* out = (float*)d_out;  // (4096, 1024) f32

  // casts
  cast_bf16_kernel<<<4096, 256, 0, stream>>>(x, xb, BL * DM / 4);
  cast_bf16_kernel<<<4096, 256, 0, stream>>>(W_in, winb, 2 * DI * DM / 4);
  cast_bf16_kernel<<<2048, 256, 0, stream>>>(W_out, woutb, DM * DI / 4);
  padcast_wxp_kernel<<<256, 256, 0, stream>>>(W_xprj, wxpb);

  // xz = x @ W_in.T   (M=4096, N=4096, K=1024)
  gemm_lds<<<dim3(32, 32, 1), 256, 0, stream>>>(xb, winb, xz, BL, 2 * DI, DM, 1);

  // x_conv = silu(conv1d(x_in))
  conv_silu_kernel<<<8192, 256, 0, stream>>>(xz, xconv, conv_w, conv_b);

  // proj partials = x_conv @ W_xproj.T, K split 8-way; then reduce
  gemm_lds<<<dim3(1, 32, 8), 256, 0, stream>>>(xconv, wxpb, projp, BL, 128, DI, 8);
  reduce_proj_kernel<<<512, 256, 0, stream>>>(projp, proj);

  // chunked scan (d-major, 2-way n-split, fully LDS-staged operands)
  scan_phase1<<<dim3(DI / 128, NB, NC - 1), 256, 0, stream>>>(proj, xconv,
                                                              A_log, W_dt,
                                                              b_dt, alpha, PH);
  scan_phase2<<<512, 256, 0, stream>>>(PH);
  scan_phase3<<<dim3(DI / 128, NB, NC), 256, 0, stream>>>(proj, xconv, xz,
                                                          A_log, D_skip, W_dt,
                                                          b_dt, alpha,
                                                          (const float*)PH, yb);

  // out = y @ W_out.T (M=4096, N=1024, K=2048), K split 2-way into dead PH
  gemm_lds<<<dim3(8, 32, 2), 256, 0, stream>>>(yb, woutb, outp, BL, DM, DI, 2);
  reduce_out_kernel<<<4096, 256, 0, stream>>>(outp, out);
}

// Round 17
// 350.194 us; speedup vs baseline: 1.0709x; 1.0370x over previous
//
#include <hip/hip_runtime.h>

// Mamba3 SSM layer: B=2, L=2048, D_MODEL=1024, D_INNER=2048, D_STATE=32
#define DM   1024
#define DI   2048
#define DST  32
#define NB   2
#define LSEQ 2048
#define BL   (NB*LSEQ)   // 4096 rows
#define LC   32          // scan chunk length
#define NC   64          // number of chunks (LC*NC == LSEQ)

using bf16   = __bf16;
using bf16x4 = __attribute__((ext_vector_type(4))) __bf16;
using bf16x8 = __attribute__((ext_vector_type(8))) __bf16;
using f32x4  = __attribute__((ext_vector_type(4))) float;
using f16x2  = __attribute__((ext_vector_type(2))) _Float16;

#define AS1(p) ((const __attribute__((address_space(1))) void*)(p))
#define AS3(p) ((__attribute__((address_space(3))) void*)(p))

static __device__ __forceinline__ float sigmoidf_(float x) {
  return 1.f / (1.f + __expf(-x));
}

static __device__ __forceinline__ f16x2 pack_f16x2(float a, float b) {
  return __builtin_bit_cast(f16x2, __builtin_amdgcn_cvt_pkrtz(a, b));
}

static __device__ __forceinline__ float exp2_(float x) {
#if __has_builtin(__builtin_amdgcn_exp2f)
  return __builtin_amdgcn_exp2f(x);
#else
  return exp2f(x);
#endif
}

// ---------------- merged prep: casts + W_xproj pad/permute ----------------
// regions (blocks): [0,4096) x; [4096,8192) W_in; [8192,10240) W_out;
// [10240,10496) W_xproj pad+permute.
__global__ __launch_bounds__(256) void prep_kernel(
    const float* __restrict__ x, const float* __restrict__ W_in,
    const float* __restrict__ W_out, const float* __restrict__ W_xprj,
    bf16* __restrict__ xb, bf16* __restrict__ winb,
    bf16* __restrict__ woutb, bf16* __restrict__ wxpb) {
  int blk = blockIdx.x;
  if (blk < 8192) {
    const float* in; bf16* out; int i;
    if (blk < 4096) { in = x; out = xb; i = blk * 256 + threadIdx.x; }
    else { in = W_in; out = winb; i = (blk - 4096) * 256 + threadIdx.x; }
    f32x4 v = ((const f32x4*)in)[i];
    bf16x4 o;
    #pragma unroll
    for (int j = 0; j < 4; ++j) o[j] = (bf16)v[j];
    ((bf16x4*)out)[i] = o;
  } else if (blk < 10240) {
    int i = (blk - 8192) * 256 + threadIdx.x;
    f32x4 v = ((const f32x4*)W_out)[i];
    bf16x4 o;
    #pragma unroll
    for (int j = 0; j < 4; ++j) o[j] = (bf16)v[j];
    ((bf16x4*)woutb)[i] = o;
  } else {
    int i = (blk - 10240) * 256 + threadIdx.x;   // over 65536
    int k4 = i & 511;
    int r  = i >> 9;
    int src = (r < 64) ? (r + 1) : ((r == 127) ? 0 : -1);
    f32x4 v = {0.f, 0.f, 0.f, 0.f};
    if (src >= 0) v = *(const f32x4*)(W_xprj + (size_t)src * 2048 + k4 * 4);
    bf16x4 o;
    #pragma unroll
    for (int j = 0; j < 4; ++j) o[j] = (bf16)v[j];
    ((bf16x4*)wxpb)[i] = o;
  }
}

// ---------------- bf16 MFMA GEMM (m97 structure): C = A * B^T ----------------
// 128x128 tile, BK=32, linear LDS [ks][128][8] staged via global_load_lds x16.
// CT = output type (float or bf16). nz>1: K-split over blockIdx.z.
template <typename CT>
__global__ __launch_bounds__(256) void gemm_lds(
    const bf16* __restrict__ A, const bf16* __restrict__ B,
    CT* __restrict__ C, int M, int N, int K, int nz) {
  __shared__ bf16 As2[4][128][8];   // 8 KB
  __shared__ bf16 Bs2[4][128][8];   // 8 KB

  int tid  = threadIdx.x;
  int bm   = blockIdx.y, bn = blockIdx.x;
  int row0 = bm * 128, col0 = bn * 128;
  int w    = tid >> 6, lane = tid & 63;
  int wr   = w >> 1, wc = w & 1;
  int lr   = lane & 15, lk = lane >> 4;

  int seg = K / nz;
  int kb  = blockIdx.z * seg, ke = kb + seg;
  CT* Cz = C + (size_t)blockIdx.z * ((size_t)M * N);

  f32x4 acc[4][4];
  #pragma unroll
  for (int i = 0; i < 4; ++i)
    #pragma unroll
    for (int j = 0; j < 4; ++j) acc[i][j] = f32x4{0.f, 0.f, 0.f, 0.f};

  // staging slots: instr i in {0,1}: j = i*256 + w*64 + lane; ks=j>>7, row=j&127
  int j0 = w * 64 + lane, j1 = 256 + w * 64 + lane;
  int ks0 = j0 >> 7, r0s = j0 & 127;
  int ks1 = j1 >> 7, r1s = j1 & 127;
  const bf16* Ag0 = A + (size_t)(row0 + r0s) * K + ks0 * 8;
  const bf16* Ag1 = A + (size_t)(row0 + r1s) * K + ks1 * 8;
  const bf16* Bg0 = B + (size_t)(col0 + r0s) * K + ks0 * 8;
  const bf16* Bg1 = B + (size_t)(col0 + r1s) * K + ks1 * 8;
  bf16* AsL = &As2[0][0][0];
  bf16* BsL = &Bs2[0][0][0];
  int base0 = (w * 64) * 8;          // shorts, wave-uniform
  int base1 = (256 + w * 64) * 8;

  for (int k0 = kb; k0 < ke; k0 += 32) {
    __builtin_amdgcn_global_load_lds(AS1(Ag0 + k0), AS3(AsL + base0), 16, 0, 0);
    __builtin_amdgcn_global_load_lds(AS1(Ag1 + k0), AS3(AsL + base1), 16, 0, 0);
    __builtin_amdgcn_global_load_lds(AS1(Bg0 + k0), AS3(BsL + base0), 16, 0, 0);
    __builtin_amdgcn_global_load_lds(AS1(Bg1 + k0), AS3(BsL + base1), 16, 0, 0);
    __syncthreads();

    bf16x8 af[4], bff[4];
    #pragma unroll
    for (int mi = 0; mi < 4; ++mi)
      af[mi] = *(const bf16x8*)&As2[lk][wr * 64 + mi * 16 + lr][0];
    #pragma unroll
    for (int ni = 0; ni < 4; ++ni)
      bff[ni] = *(const bf16x8*)&Bs2[lk][wc * 64 + ni * 16 + lr][0];

    #pragma unroll
    for (int mi = 0; mi < 4; ++mi)
      #pragma unroll
      for (int ni = 0; ni < 4; ++ni)
        acc[mi][ni] = __builtin_amdgcn_mfma_f32_16x16x32_bf16(
            af[mi], bff[ni], acc[mi][ni], 0, 0, 0);
    __syncthreads();
  }

  // C/D layout: col = lane&15, row = (lane>>4)*4 + reg
  #pragma unroll
  for (int mi = 0; mi < 4; ++mi)
    #pragma unroll
    for (int ni = 0; ni < 4; ++ni) {
      int r0 = row0 + wr * 64 + mi * 16 + lk * 4;
      int c  = col0 + wc * 64 + ni * 16 + lr;
      #pragma unroll
      for (int r = 0; r < 4; ++r)
        Cz[(size_t)(r0 + r) * N + c] = (CT)acc[mi][ni][r];
    }
}

// reduce 8 K-split partials -> proj
__global__ __launch_bounds__(256) void reduce_proj_kernel(
    const float* __restrict__ part, float* __restrict__ proj) {
  int i = blockIdx.x * 256 + threadIdx.x;   // over 4096*128/4 = 131072
  f32x4 s = ((const f32x4*)part)[i];
  #pragma unroll
  for (int z = 1; z < 8; ++z) s += ((const f32x4*)part)[(size_t)z * 131072 + i];
  ((f32x4*)proj)[i] = s;
}

// reduce 2 K-split partials -> out
__global__ __launch_bounds__(256) void reduce_out_kernel(
    const float* __restrict__ part, float* __restrict__ out) {
  int i = blockIdx.x * 256 + threadIdx.x;   // over 4096*1024/4 = 1,048,576
  f32x4 s = ((const f32x4*)part)[i];
  s += ((const f32x4*)part)[(size_t)1048576 + i];
  ((f32x4*)out)[i] = s;
}

// ---------------- depthwise conv3 + SiLU -> bf16 (bf16 xz input) -------------
__global__ __launch_bounds__(256) void conv_silu_kernel(
    const bf16* __restrict__ xzb, bf16* __restrict__ xconv,
    const float* __restrict__ conv_w, const float* __restrict__ conv_b) {
  int i = blockIdx.x * 256 + threadIdx.x;  // over BL * DI/4
  int d4 = i & 511;
  int d  = d4 * 4;
  int bl = i >> 9;
  int l  = bl & (LSEQ - 1);

  const bf16* base = xzb + (size_t)bl * (2 * DI) + d;
  bf16x4 zero4 = {(bf16)0.f, (bf16)0.f, (bf16)0.f, (bf16)0.f};
  bf16x4 xm = (l > 0)        ? *(const bf16x4*)(base - 2 * DI) : zero4;
  bf16x4 xc = *(const bf16x4*)(base);
  bf16x4 xp = (l < LSEQ - 1) ? *(const bf16x4*)(base + 2 * DI) : zero4;

  bf16x4 o;
  #pragma unroll
  for (int j = 0; j < 4; ++j) {
    float w0 = conv_w[(d + j) * 3 + 0];
    float w1 = conv_w[(d + j) * 3 + 1];
    float w2 = conv_w[(d + j) * 3 + 2];
    float v = fmaf(w0, (float)xm[j],
              fmaf(w1, (float)xc[j],
              fmaf(w2, (float)xp[j], conv_b[d + j])));
    v = v * sigmoidf_(v);
    o[j] = (bf16)v;
  }
  *(bf16x4*)(xconv + (size_t)bl * DI + d) = o;
}

// ---------------- chunked SSM scan, d-major, 2-way n-split, LDS-staged -------
// lane = (d&31) + 32*nh; 16 states/thread. Block 256 = 4 waves covers d-range
// of 128 for one (b,c). All per-step operands (B, C, dtraw, u, g) staged in
// LDS -> inner loop has ZERO global accesses.

// phase1: launch_bounds (256,4) -- r14 proven (r12 lesson: tighter caps spill).
__global__ __launch_bounds__(256, 4) void scan_phase1(
    const float* __restrict__ proj, const bf16* __restrict__ xconv,
    const float* __restrict__ A_log, const float* __restrict__ W_dt,
    const float* __restrict__ b_dt, const float* __restrict__ alpha,
    unsigned int* __restrict__ PH) {
  __shared__ float Bs[LC][32];    // 4 KB: B values of the chunk
  __shared__ bf16  Us[LC][128];   // 8 KB: u values of the chunk
  __shared__ float Ds[LC];        // dtraw per step
  int tid = threadIdx.x;
  int wid = tid >> 6, lane = tid & 63;
  int dl = lane & 31, nh = lane >> 5;
  int di = wid * 32 + dl;              // d index within block's 128
  int d = blockIdx.x * 128 + di;
  int b = blockIdx.y, c = blockIdx.z;
  int n0 = nh * 16;

  const float* pb = proj + ((size_t)b * LSEQ + c * LC) * 128;
  const bf16*  ub = xconv + ((size_t)b * LSEQ + c * LC) * DI + blockIdx.x * 128;

  // stage B: slot s = tid (256 slots of 16B): row r=s>>3, quad q=s&7
  {
    const float* g = pb + (size_t)(tid >> 3) * 128 + (tid & 7) * 4;
    __builtin_amdgcn_global_load_lds(AS1(g), AS3((char*)&Bs[0][0] + wid * 1024),
                                     16, 0, 0);
  }
  // stage U: 512 slots of 16B (8 bf16): row s>>4, oct s&15
  #pragma unroll
  for (int k = 0; k < 2; ++k) {
    int s = k * 256 + wid * 64 + lane;
    const bf16* g = ub + (size_t)(s >> 4) * DI + (s & 15) * 8;
    __builtin_amdgcn_global_load_lds(AS1(g),
        AS3((char*)&Us[0][0] + (k * 256 + wid * 64) * 16), 16, 0, 0);
  }
  if (tid < LC) Ds[tid] = pb[(size_t)tid * 128 + 127];

  float aG = sigmoidf_(alpha[0]), omA = 1.f - aG;
  float Wd = W_dt[d], bd = b_dt[d];

  float Ar2[16];   // -exp(A_log)*log2(e)
  #pragma unroll
  for (int n = 0; n < 16; n += 4) {
    f32x4 al = *(const f32x4*)(A_log + (size_t)d * DST + n0 + n);
    #pragma unroll
    for (int j = 0; j < 4; ++j) Ar2[n + j] = -__expf(al[j]) * 1.44269504f;
  }

  float h[16], P[16];
  #pragma unroll
  for (int n = 0; n < 16; ++n) { h[n] = 0.f; P[n] = 1.f; }

  __syncthreads();

  #pragma unroll 2
  for (int t = 0; t < LC; ++t) {
    float dtraw = Ds[t];
    float u = (float)Us[t][di];
    float s = fmaf(dtraw, Wd, bd);
    float dt = (s > 15.f) ? s : __logf(1.f + __expf(s));  // softplus
    float dtu = dt * u;
    #pragma unroll
    for (int n4 = 0; n4 < 4; ++n4) {
      f32x4 Bq = *(const f32x4*)&Bs[t][((n0 + n4 * 4) & 31)];
      #pragma unroll
      for (int j = 0; j < 4; ++j) {
        int n = n4 * 4 + j;
        float t1  = dt * Ar2[n];                       // dtA*log2e
        float ex  = exp2_(t1);
        float den = fmaf(t1, -0.34657359f, 1.000001f); // 1 - 0.5*dtA + 1e-6
        float Ad  = fmaf(aG, ex, omA * __builtin_amdgcn_rcpf(den));
        P[n] *= Ad;
        h[n] = fmaf(Ad, h[n], dtu * Bq[j]);
      }
    }
  }
  size_t ob = (((size_t)c * NB + b) * DI + d) * DST + n0;
  #pragma unroll
  for (int n4 = 0; n4 < 4; ++n4) {
    uint4 o;
    #pragma unroll
    for (int j = 0; j < 4; ++j) {
      int n = n4 * 4 + j;
      ((unsigned int*)&o)[j] =
          __builtin_bit_cast(unsigned int, pack_f16x2(P[n], h[n]));
    }
    *(uint4*)(PH + ob + n4 * 4) = o;
  }
}

// thread per (b,d,n): serial combine over NC chunks; in-place packed->f32.
__global__ __launch_bounds__(256) void scan_phase2(unsigned int* __restrict__ PH) {
  int i = blockIdx.x * 256 + threadIdx.x;   // 0 .. NB*DI*DST-1 = 131071
  float H = 0.f;
  #pragma unroll 4
  for (int c = 0; c < NC; ++c) {
    size_t idx = (size_t)c * (NB * DI * DST) + i;
    f16x2 ph = __builtin_bit_cast(f16x2, PH[idx]);
    ((float*)PH)[idx] = H;                        // start state for chunk c
    H = fmaf((float)ph[0], H, (float)ph[1]);      // end state of chunk c
  }
}

// phase3: re-run chunk from true start state; LDS-staged B/C/dtraw/u/g.
// g = silu(z) computed from bf16 z during staging (read-only; no WAR race).
__global__ __launch_bounds__(256, 6) void scan_phase3(
    const float* __restrict__ proj, const bf16* __restrict__ xconv,
    const bf16* __restrict__ xzb,    // z at col 2048+d (bf16 rows of 4096)
    const float* __restrict__ A_log, const float* __restrict__ D_skip,
    const float* __restrict__ W_dt, const float* __restrict__ b_dt,
    const float* __restrict__ alpha, const float* __restrict__ PH,
    bf16* __restrict__ yb) {
  __shared__ float    BCs[LC][64];  // 8 KB: B|C values of the chunk
  __shared__ bf16     Us[LC][128];  // 8 KB: u values
  __shared__ _Float16 Gs[LC][128];  // 8 KB: silu(z) values
  __shared__ float    Ds[LC];       // dtraw per step
  int tid = threadIdx.x;
  int wid = tid >> 6, lane = tid & 63;
  int dl = lane & 31, nh = lane >> 5;
  int di = wid * 32 + dl;
  int d = blockIdx.x * 128 + di;
  int b = blockIdx.y, c = blockIdx.z;
  int n0 = nh * 16;

  const float* pb = proj + ((size_t)b * LSEQ + c * LC) * 128;
  const bf16*  ub = xconv + ((size_t)b * LSEQ + c * LC) * DI + blockIdx.x * 128;
  const bf16*  zb = xzb + ((size_t)b * LSEQ + c * LC) * (2 * DI) + 2048
                    + blockIdx.x * 128;

  // stage B|C: slots s = tid, tid+256 (512 slots): row s>>4, quad s&15
  {
    const float* g0 = pb + (size_t)(tid >> 4) * 128 + (tid & 15) * 4;
    int s1 = tid + 256;
    const float* g1 = pb + (size_t)(s1 >> 4) * 128 + (s1 & 15) * 4;
    char* base = (char*)&BCs[0][0];
    __builtin_amdgcn_global_load_lds(AS1(g0), AS3(base + wid * 1024), 16, 0, 0);
    __builtin_amdgcn_global_load_lds(AS1(g1), AS3(base + 4096 + wid * 1024),
                                     16, 0, 0);
  }
  // stage U: 512 slots of 16B: row s>>4, oct s&15
  #pragma unroll
  for (int k = 0; k < 2; ++k) {
    int s = k * 256 + wid * 64 + lane;
    const bf16* g = ub + (size_t)(s >> 4) * DI + (s & 15) * 8;
    __builtin_amdgcn_global_load_lds(AS1(g),
        AS3((char*)&Us[0][0] + (k * 256 + wid * 64) * 16), 16, 0, 0);
  }
  // stage G: 512 bf16x8 slots -> silu -> f16, reg-staged (2 slots/thread)
  #pragma unroll
  for (int k = 0; k < 2; ++k) {
    int s = k * 256 + tid;
    int row = s >> 4, oct = s & 15;
    bf16x8 zv = *(const bf16x8*)(zb + (size_t)row * (2 * DI) + oct * 8);
    uint4 o;
    #pragma unroll
    for (int q = 0; q < 4; ++q) {
      float z0 = (float)zv[2 * q], z1 = (float)zv[2 * q + 1];
      ((unsigned int*)&o)[q] = __builtin_bit_cast(unsigned int,
          pack_f16x2(z0 * sigmoidf_(z0), z1 * sigmoidf_(z1)));
    }
    *(uint4*)&Gs[row][oct * 8] = o;
  }
  if (tid < LC) Ds[tid] = pb[(size_t)tid * 128 + 127];

  float aG = sigmoidf_(alpha[0]), omA = 1.f - aG;
  float Dsk = D_skip[d];
  float Wd = W_dt[d], bd = b_dt[d];

  float Ar2[16];
  #pragma unroll
  for (int n = 0; n < 16; n += 4) {
    f32x4 al = *(const f32x4*)(A_log + (size_t)d * DST + n0 + n);
    #pragma unroll
    for (int j = 0; j < 4; ++j) Ar2[n + j] = -__expf(al[j]) * 1.44269504f;
  }

  float h[16];
  size_t ob = (((size_t)c * NB + b) * DI + d) * DST + n0;
  #pragma unroll
  for (int n = 0; n < 16; n += 4) {
    f32x4 hv = *(const f32x4*)(PH + ob + n);
    #pragma unroll
    for (int j = 0; j < 4; ++j) h[n + j] = hv[j];
  }

  bf16* yc = yb + ((size_t)b * LSEQ + c * LC) * DI + d;

  __syncthreads();

  #pragma unroll 2
  for (int t = 0; t < LC; ++t) {
    float dtraw = Ds[t];
    float u = (float)Us[t][di];
    float s = fmaf(dtraw, Wd, bd);
    float dt = (s > 15.f) ? s : __logf(1.f + __expf(s));  // softplus
    float dtu = dt * u;
    float p0 = 0.f, p1 = 0.f, p2 = 0.f, p3 = 0.f;
    #pragma unroll
    for (int n4 = 0; n4 < 4; ++n4) {
      f32x4 Bq = *(const f32x4*)&BCs[t][n0 + n4 * 4];
      f32x4 Cq = *(const f32x4*)&BCs[t][32 + n0 + n4 * 4];
      #pragma unroll
      for (int j = 0; j < 4; ++j) {
        int n = n4 * 4 + j;
        float t1  = dt * Ar2[n];
        float ex  = exp2_(t1);
        float den = fmaf(t1, -0.34657359f, 1.000001f);
        float Ad  = fmaf(aG, ex, omA * __builtin_amdgcn_rcpf(den));
        h[n] = fmaf(Ad, h[n], dtu * Bq[j]);
        if (j == 0)      p0 = fmaf(Cq[j], h[n], p0);
        else if (j == 1) p1 = fmaf(Cq[j], h[n], p1);
        else if (j == 2) p2 = fmaf(Cq[j], h[n], p2);
        else             p3 = fmaf(Cq[j], h[n], p3);
      }
    }
    float part = (p0 + p1) + (p2 + p3);
    part += __shfl_xor(part, 32);   // combine the two 16-state halves
    if (nh == 0) {
      float g = (float)Gs[t][di];
      float y = fmaf(Dsk, u, part) * g;
      yc[(size_t)t * DI] = (bf16)y;
    }
  }
}

// ---------------- launch ----------------
extern "C" void kernel_launch(void* const* d_in, const int* in_sizes, int n_in,
                              void* d_out, int out_size, void* d_ws, size_t ws_size,
                              hipStream_t stream) {
  const float* x      = (const float*)d_in[0];
  const float* W_in   = (const float*)d_in[1];
  const float* conv_w = (const float*)d_in[2];
  const float* conv_b = (const float*)d_in[3];
  const float* A_log  = (const float*)d_in[4];
  const float* D_skip = (const float*)d_in[5];
  const float* W_xprj = (const float*)d_in[6];
  const float* W_dt   = (const float*)d_in[7];
  const float* b_dt   = (const float*)d_in[8];
  const float* alpha  = (const float*)d_in[9];
  const float* W_out  = (const float*)d_in[10];

  char* ws = (char*)d_ws;
  // Layout (within proven 141,033,472 B):
  bf16*  xzb   = (bf16*) (ws + 0);             // (4096,4096) bf16: 33,554,432
  bf16*  xconv = (bf16*) (ws + 67108864);      // (4096,2048) bf16: 16,777,216
  float* proj  = (float*)(ws + 83886080);      // (4096,128)  f32:   2,097,152
  bf16*  woutb = (bf16*) (ws + 85983232);      // (1024,2048) bf16:  4,194,304
  bf16*  wxpb  = (bf16*) (ws + 90177536);      // (128,2048)  bf16:    524,288
  bf16*  yb    = (bf16*) (ws + 90701824);      // (4096,2048) bf16: 16,777,216
  unsigned int* PH = (unsigned int*)(ws + 107479040);  // NC*NB*DI*DST u32: 33,554,432
  // overlays of the PH region (all dead before phase1 writes PH):
  bf16*  xb    = (bf16*) (ws + 107479040);     // (4096,1024) bf16: 8,388,608 (dead after GEMM1)
  bf16*  winb  = (bf16*) (ws + 115867648);     // (4096,1024) bf16: 8,388,608 (dead after GEMM1)
  float* projp = (float*)(ws + 107479040);     // 8x(4096,128) f32: 16,777,216 (dead after reduce)
  // after phase3, PH is dead again -> GEMM3 partials (2x4096x1024 f32 = 33.5 MB)
  float* outp  = (float*)(ws + 107479040);

  float* out = (float*)d_out;  // (4096, 1024) f32

  // merged casts + pad/permute
  prep_kernel<<<10496, 256, 0, stream>>>(x, W_in, W_out, W_xprj,
                                         xb, winb, woutb, wxpb);

  // xz = x @ W_in.T   (M=4096, N=4096, K=1024) -> bf16
  gemm_lds<bf16><<<dim3(32, 32, 1), 256, 0, stream>>>(xb, winb, xzb,
                                                      BL, 2 * DI, DM, 1);

  // x_conv = silu(conv1d(x_in))  (bf16 in/out)
  conv_silu_kernel<<<8192, 256, 0, stream>>>(xzb, xconv, conv_w, conv_b);

  // proj partials = x_conv @ W_xproj.T, K split 8-way; then reduce
  gemm_lds<float><<<dim3(1, 32, 8), 256, 0, stream>>>(xconv, wxpb, projp,
                                                      BL, 128, DI, 8);
  reduce_proj_kernel<<<512, 256, 0, stream>>>(projp, proj);

  // chunked scan (d-major, 2-way n-split, fully LDS-staged operands)
  scan_phase1<<<dim3(DI / 128, NB, NC - 1), 256, 0, stream>>>(proj, xconv,
                                                              A_log, W_dt,
                                                              b_dt, alpha, PH);
  scan_phase2<<<512, 256, 0, stream>>>(PH);
  scan_phase3<<<dim3(DI / 128, NB, NC), 256, 0, stream>>>(proj, xconv, xzb,
                                                          A_log, D_skip, W_dt,
                                                          b_dt, alpha,
                                                          (const float*)PH, yb);

  // out = y @ W_out.T (M=4096, N=1024, K=2048), K split 2-way into dead PH
  gemm_lds<float><<<dim3(8, 32, 2), 256, 0, stream>>>(yb, woutb, outp,
                                                      BL, DM, DI, 2);
  reduce_out_kernel<<<4096, 256, 0, stream>>>(outp, out);
}

// Round 18
// 337.593 us; speedup vs baseline: 1.1109x; 1.0373x over previous
//
#include <hip/hip_runtime.h>

// Mamba3 SSM layer: B=2, L=2048, D_MODEL=1024, D_INNER=2048, D_STATE=32
#define DM   1024
#define DI   2048
#define DST  32
#define NB   2
#define LSEQ 2048
#define BL   (NB*LSEQ)   // 4096 rows
#define LC   32          // scan chunk length
#define NC   64          // number of chunks (LC*NC == LSEQ)

using bf16   = __bf16;
using bf16x4 = __attribute__((ext_vector_type(4))) __bf16;
using bf16x8 = __attribute__((ext_vector_type(8))) __bf16;
using f32x4  = __attribute__((ext_vector_type(4))) float;
using f16x2  = __attribute__((ext_vector_type(2))) _Float16;

#define AS1(p) ((const __attribute__((address_space(1))) void*)(p))
#define AS3(p) ((__attribute__((address_space(3))) void*)(p))

static __device__ __forceinline__ float sigmoidf_(float x) {
  return 1.f / (1.f + __expf(-x));
}

static __device__ __forceinline__ f16x2 pack_f16x2(float a, float b) {
  return __builtin_bit_cast(f16x2, __builtin_amdgcn_cvt_pkrtz(a, b));
}

static __device__ __forceinline__ float exp2_(float x) {
#if __has_builtin(__builtin_amdgcn_exp2f)
  return __builtin_amdgcn_exp2f(x);
#else
  return exp2f(x);
#endif
}

// ---------------- merged prep: casts + W_xproj pad/permute ----------------
// regions (blocks): [0,4096) x; [4096,8192) W_in; [8192,10240) W_out;
// [10240,10496) W_xproj pad+permute.
__global__ __launch_bounds__(256) void prep_kernel(
    const float* __restrict__ x, const float* __restrict__ W_in,
    const float* __restrict__ W_out, const float* __restrict__ W_xprj,
    bf16* __restrict__ xb, bf16* __restrict__ winb,
    bf16* __restrict__ woutb, bf16* __restrict__ wxpb) {
  int blk = blockIdx.x;
  if (blk < 8192) {
    const float* in; bf16* out; int i;
    if (blk < 4096) { in = x; out = xb; i = blk * 256 + threadIdx.x; }
    else { in = W_in; out = winb; i = (blk - 4096) * 256 + threadIdx.x; }
    f32x4 v = ((const f32x4*)in)[i];
    bf16x4 o;
    #pragma unroll
    for (int j = 0; j < 4; ++j) o[j] = (bf16)v[j];
    ((bf16x4*)out)[i] = o;
  } else if (blk < 10240) {
    int i = (blk - 8192) * 256 + threadIdx.x;
    f32x4 v = ((const f32x4*)W_out)[i];
    bf16x4 o;
    #pragma unroll
    for (int j = 0; j < 4; ++j) o[j] = (bf16)v[j];
    ((bf16x4*)woutb)[i] = o;
  } else {
    int i = (blk - 10240) * 256 + threadIdx.x;   // over 65536
    int k4 = i & 511;
    int r  = i >> 9;
    int src = (r < 64) ? (r + 1) : ((r == 127) ? 0 : -1);
    f32x4 v = {0.f, 0.f, 0.f, 0.f};
    if (src >= 0) v = *(const f32x4*)(W_xprj + (size_t)src * 2048 + k4 * 4);
    bf16x4 o;
    #pragma unroll
    for (int j = 0; j < 4; ++j) o[j] = (bf16)v[j];
    ((bf16x4*)wxpb)[i] = o;
  }
}

// ---------------- bf16 MFMA GEMM: C = A * B^T, BK=64 ----------------
// 128x128 tile, BK=64 (2 half-K substeps per barrier pair -> half the
// vmcnt(0) barrier drains of the BK=32 m97 structure). Linear LDS
// [8][128][8] staged via 8x global_load_lds width-16.
// CT = output type (float or bf16). nz>1: K-split over blockIdx.z.
template <typename CT>
__global__ __launch_bounds__(256) void gemm_lds(
    const bf16* __restrict__ A, const bf16* __restrict__ B,
    CT* __restrict__ C, int M, int N, int K, int nz) {
  __shared__ bf16 As2[8][128][8];   // 16 KB
  __shared__ bf16 Bs2[8][128][8];   // 16 KB

  int tid  = threadIdx.x;
  int bm   = blockIdx.y, bn = blockIdx.x;
  int row0 = bm * 128, col0 = bn * 128;
  int w    = tid >> 6, lane = tid & 63;
  int wr   = w >> 1, wc = w & 1;
  int lr   = lane & 15, lk = lane >> 4;

  int seg = K / nz;
  int kb  = blockIdx.z * seg, ke = kb + seg;
  CT* Cz = C + (size_t)blockIdx.z * ((size_t)M * N);

  f32x4 acc[4][4];
  #pragma unroll
  for (int i = 0; i < 4; ++i)
    #pragma unroll
    for (int j = 0; j < 4; ++j) acc[i][j] = f32x4{0.f, 0.f, 0.f, 0.f};

  // staging: instr i in {0..3} per matrix covers slots j = i*256 + w*64 + lane
  // ks = j>>7 (0..7 K-slab page), row = j&127.
  const bf16* Ag[4];
  const bf16* Bg[4];
  int lbase[4];
  #pragma unroll
  for (int i = 0; i < 4; ++i) {
    int j  = i * 256 + w * 64 + lane;
    int ks = j >> 7, row = j & 127;
    Ag[i] = A + (size_t)(row0 + row) * K + ks * 8;
    Bg[i] = B + (size_t)(col0 + row) * K + ks * 8;
    lbase[i] = (i * 256 + w * 64) * 8;   // shorts, wave-uniform
  }
  bf16* AsL = &As2[0][0][0];
  bf16* BsL = &Bs2[0][0][0];

  for (int k0 = kb; k0 < ke; k0 += 64) {
    #pragma unroll
    for (int i = 0; i < 4; ++i)
      __builtin_amdgcn_global_load_lds(AS1(Ag[i] + k0), AS3(AsL + lbase[i]),
                                       16, 0, 0);
    #pragma unroll
    for (int i = 0; i < 4; ++i)
      __builtin_amdgcn_global_load_lds(AS1(Bg[i] + k0), AS3(BsL + lbase[i]),
                                       16, 0, 0);
    __syncthreads();

    #pragma unroll
    for (int half = 0; half < 2; ++half) {
      int lk2 = half * 4 + lk;
      bf16x8 af[4], bff[4];
      #pragma unroll
      for (int mi = 0; mi < 4; ++mi)
        af[mi] = *(const bf16x8*)&As2[lk2][wr * 64 + mi * 16 + lr][0];
      #pragma unroll
      for (int ni = 0; ni < 4; ++ni)
        bff[ni] = *(const bf16x8*)&Bs2[lk2][wc * 64 + ni * 16 + lr][0];

      #pragma unroll
      for (int mi = 0; mi < 4; ++mi)
        #pragma unroll
        for (int ni = 0; ni < 4; ++ni)
          acc[mi][ni] = __builtin_amdgcn_mfma_f32_16x16x32_bf16(
              af[mi], bff[ni], acc[mi][ni], 0, 0, 0);
    }
    __syncthreads();
  }

  // C/D layout: col = lane&15, row = (lane>>4)*4 + reg
  #pragma unroll
  for (int mi = 0; mi < 4; ++mi)
    #pragma unroll
    for (int ni = 0; ni < 4; ++ni) {
      int r0 = row0 + wr * 64 + mi * 16 + lk * 4;
      int c  = col0 + wc * 64 + ni * 16 + lr;
      #pragma unroll
      for (int r = 0; r < 4; ++r)
        Cz[(size_t)(r0 + r) * N + c] = (CT)acc[mi][ni][r];
    }
}

// reduce 8 K-split partials -> proj
__global__ __launch_bounds__(256) void reduce_proj_kernel(
    const float* __restrict__ part, float* __restrict__ proj) {
  int i = blockIdx.x * 256 + threadIdx.x;   // over 4096*128/4 = 131072
  f32x4 s = ((const f32x4*)part)[i];
  #pragma unroll
  for (int z = 1; z < 8; ++z) s += ((const f32x4*)part)[(size_t)z * 131072 + i];
  ((f32x4*)proj)[i] = s;
}

// reduce 2 K-split partials -> out
__global__ __launch_bounds__(256) void reduce_out_kernel(
    const float* __restrict__ part, float* __restrict__ out) {
  int i = blockIdx.x * 256 + threadIdx.x;   // over 4096*1024/4 = 1,048,576
  f32x4 s = ((const f32x4*)part)[i];
  s += ((const f32x4*)part)[(size_t)1048576 + i];
  ((f32x4*)out)[i] = s;
}

// ---------------- depthwise conv3 + SiLU -> bf16 (bf16 xz input) -------------
__global__ __launch_bounds__(256) void conv_silu_kernel(
    const bf16* __restrict__ xzb, bf16* __restrict__ xconv,
    const float* __restrict__ conv_w, const float* __restrict__ conv_b) {
  int i = blockIdx.x * 256 + threadIdx.x;  // over BL * DI/4
  int d4 = i & 511;
  int d  = d4 * 4;
  int bl = i >> 9;
  int l  = bl & (LSEQ - 1);

  const bf16* base = xzb + (size_t)bl * (2 * DI) + d;
  bf16x4 zero4 = {(bf16)0.f, (bf16)0.f, (bf16)0.f, (bf16)0.f};
  bf16x4 xm = (l > 0)        ? *(const bf16x4*)(base - 2 * DI) : zero4;
  bf16x4 xc = *(const bf16x4*)(base);
  bf16x4 xp = (l < LSEQ - 1) ? *(const bf16x4*)(base + 2 * DI) : zero4;

  bf16x4 o;
  #pragma unroll
  for (int j = 0; j < 4; ++j) {
    float w0 = conv_w[(d + j) * 3 + 0];
    float w1 = conv_w[(d + j) * 3 + 1];
    float w2 = conv_w[(d + j) * 3 + 2];
    float v = fmaf(w0, (float)xm[j],
              fmaf(w1, (float)xc[j],
              fmaf(w2, (float)xp[j], conv_b[d + j])));
    v = v * sigmoidf_(v);
    o[j] = (bf16)v;
  }
  *(bf16x4*)(xconv + (size_t)bl * DI + d) = o;
}

// ---------------- chunked SSM scan, d-major, 2-way n-split, LDS-staged -------
// lane = (d&31) + 32*nh; 16 states/thread. Block 256 = 4 waves covers d-range
// of 128 for one (b,c). All per-step operands (B, C, dtraw, u, g) staged in
// LDS -> inner loop has ZERO global accesses.

// phase1: launch_bounds (256,4) -- r14 proven (r12 lesson: tighter caps spill).
__global__ __launch_bounds__(256, 4) void scan_phase1(
    const float* __restrict__ proj, const bf16* __restrict__ xconv,
    const float* __restrict__ A_log, const float* __restrict__ W_dt,
    const float* __restrict__ b_dt, const float* __restrict__ alpha,
    unsigned int* __restrict__ PH) {
  __shared__ float Bs[LC][32];    // 4 KB: B values of the chunk
  __shared__ bf16  Us[LC][128];   // 8 KB: u values of the chunk
  __shared__ float Ds[LC];        // dtraw per step
  int tid = threadIdx.x;
  int wid = tid >> 6, lane = tid & 63;
  int dl = lane & 31, nh = lane >> 5;
  int di = wid * 32 + dl;              // d index within block's 128
  int d = blockIdx.x * 128 + di;
  int b = blockIdx.y, c = blockIdx.z;
  int n0 = nh * 16;

  const float* pb = proj + ((size_t)b * LSEQ + c * LC) * 128;
  const bf16*  ub = xconv + ((size_t)b * LSEQ + c * LC) * DI + blockIdx.x * 128;

  // stage B: slot s = tid (256 slots of 16B): row r=s>>3, quad q=s&7
  {
    const float* g = pb + (size_t)(tid >> 3) * 128 + (tid & 7) * 4;
    __builtin_amdgcn_global_load_lds(AS1(g), AS3((char*)&Bs[0][0] + wid * 1024),
                                     16, 0, 0);
  }
  // stage U: 512 slots of 16B (8 bf16): row s>>4, oct s&15
  #pragma unroll
  for (int k = 0; k < 2; ++k) {
    int s = k * 256 + wid * 64 + lane;
    const bf16* g = ub + (size_t)(s >> 4) * DI + (s & 15) * 8;
    __builtin_amdgcn_global_load_lds(AS1(g),
        AS3((char*)&Us[0][0] + (k * 256 + wid * 64) * 16), 16, 0, 0);
  }
  if (tid < LC) Ds[tid] = pb[(size_t)tid * 128 + 127];

  float aG = sigmoidf_(alpha[0]), omA = 1.f - aG;
  float Wd = W_dt[d], bd = b_dt[d];

  float Ar2[16];   // -exp(A_log)*log2(e)
  #pragma unroll
  for (int n = 0; n < 16; n += 4) {
    f32x4 al = *(const f32x4*)(A_log + (size_t)d * DST + n0 + n);
    #pragma unroll
    for (int j = 0; j < 4; ++j) Ar2[n + j] = -__expf(al[j]) * 1.44269504f;
  }

  float h[16], P[16];
  #pragma unroll
  for (int n = 0; n < 16; ++n) { h[n] = 0.f; P[n] = 1.f; }

  __syncthreads();

  #pragma unroll 2
  for (int t = 0; t < LC; ++t) {
    float dtraw = Ds[t];
    float u = (float)Us[t][di];
    float s = fmaf(dtraw, Wd, bd);
    float dt = (s > 15.f) ? s : __logf(1.f + __expf(s));  // softplus
    float dtu = dt * u;
    #pragma unroll
    for (int n4 = 0; n4 < 4; ++n4) {
      f32x4 Bq = *(const f32x4*)&Bs[t][((n0 + n4 * 4) & 31)];
      #pragma unroll
      for (int j = 0; j < 4; ++j) {
        int n = n4 * 4 + j;
        float t1  = dt * Ar2[n];                       // dtA*log2e
        float ex  = exp2_(t1);
        float den = fmaf(t1, -0.34657359f, 1.000001f); // 1 - 0.5*dtA + 1e-6
        float Ad  = fmaf(aG, ex, omA * __builtin_amdgcn_rcpf(den));
        P[n] *= Ad;
        h[n] = fmaf(Ad, h[n], dtu * Bq[j]);
      }
    }
  }
  size_t ob = (((size_t)c * NB + b) * DI + d) * DST + n0;
  #pragma unroll
  for (int n4 = 0; n4 < 4; ++n4) {
    uint4 o;
    #pragma unroll
    for (int j = 0; j < 4; ++j) {
      int n = n4 * 4 + j;
      ((unsigned int*)&o)[j] =
          __builtin_bit_cast(unsigned int, pack_f16x2(P[n], h[n]));
    }
    *(uint4*)(PH + ob + n4 * 4) = o;
  }
}

// thread per (b,d,n): serial combine over NC chunks; in-place packed->f32.
__global__ __launch_bounds__(256) void scan_phase2(unsigned int* __restrict__ PH) {
  int i = blockIdx.x * 256 + threadIdx.x;   // 0 .. NB*DI*DST-1 = 131071
  float H = 0.f;
  #pragma unroll 4
  for (int c = 0; c < NC; ++c) {
    size_t idx = (size_t)c * (NB * DI * DST) + i;
    f16x2 ph = __builtin_bit_cast(f16x2, PH[idx]);
    ((float*)PH)[idx] = H;                        // start state for chunk c
    H = fmaf((float)ph[0], H, (float)ph[1]);      // end state of chunk c
  }
}

// phase3: re-run chunk from true start state; LDS-staged B/C/dtraw/u/g.
// g = silu(z) computed from bf16 z during staging (read-only; no WAR race).
__global__ __launch_bounds__(256, 6) void scan_phase3(
    const float* __restrict__ proj, const bf16* __restrict__ xconv,
    const bf16* __restrict__ xzb,    // z at col 2048+d (bf16 rows of 4096)
    const float* __restrict__ A_log, const float* __restrict__ D_skip,
    const float* __restrict__ W_dt, const float* __restrict__ b_dt,
    const float* __restrict__ alpha, const float* __restrict__ PH,
    bf16* __restrict__ yb) {
  __shared__ float    BCs[LC][64];  // 8 KB: B|C values of the chunk
  __shared__ bf16     Us[LC][128];  // 8 KB: u values
  __shared__ _Float16 Gs[LC][128];  // 8 KB: silu(z) values
  __shared__ float    Ds[LC];       // dtraw per step
  int tid = threadIdx.x;
  int wid = tid >> 6, lane = tid & 63;
  int dl = lane & 31, nh = lane >> 5;
  int di = wid * 32 + dl;
  int d = blockIdx.x * 128 + di;
  int b = blockIdx.y, c = blockIdx.z;
  int n0 = nh * 16;

  const float* pb = proj + ((size_t)b * LSEQ + c * LC) * 128;
  const bf16*  ub = xconv + ((size_t)b * LSEQ + c * LC) * DI + blockIdx.x * 128;
  const bf16*  zb = xzb + ((size_t)b * LSEQ + c * LC) * (2 * DI) + 2048
                    + blockIdx.x * 128;

  // stage B|C: slots s = tid, tid+256 (512 slots): row s>>4, quad s&15
  {
    const float* g0 = pb + (size_t)(tid >> 4) * 128 + (tid & 15) * 4;
    int s1 = tid + 256;
    const float* g1 = pb + (size_t)(s1 >> 4) * 128 + (s1 & 15) * 4;
    char* base = (char*)&BCs[0][0];
    __builtin_amdgcn_global_load_lds(AS1(g0), AS3(base + wid * 1024), 16, 0, 0);
    __builtin_amdgcn_global_load_lds(AS1(g1), AS3(base + 4096 + wid * 1024),
                                     16, 0, 0);
  }
  // stage U: 512 slots of 16B: row s>>4, oct s&15
  #pragma unroll
  for (int k = 0; k < 2; ++k) {
    int s = k * 256 + wid * 64 + lane;
    const bf16* g = ub + (size_t)(s >> 4) * DI + (s & 15) * 8;
    __builtin_amdgcn_global_load_lds(AS1(g),
        AS3((char*)&Us[0][0] + (k * 256 + wid * 64) * 16), 16, 0, 0);
  }
  // stage G: 512 bf16x8 slots -> silu -> f16, reg-staged (2 slots/thread)
  #pragma unroll
  for (int k = 0; k < 2; ++k) {
    int s = k * 256 + tid;
    int row = s >> 4, oct = s & 15;
    bf16x8 zv = *(const bf16x8*)(zb + (size_t)row * (2 * DI) + oct * 8);
    uint4 o;
    #pragma unroll
    for (int q = 0; q < 4; ++q) {
      float z0 = (float)zv[2 * q], z1 = (float)zv[2 * q + 1];
      ((unsigned int*)&o)[q] = __builtin_bit_cast(unsigned int,
          pack_f16x2(z0 * sigmoidf_(z0), z1 * sigmoidf_(z1)));
    }
    *(uint4*)&Gs[row][oct * 8] = o;
  }
  if (tid < LC) Ds[tid] = pb[(size_t)tid * 128 + 127];

  float aG = sigmoidf_(alpha[0]), omA = 1.f - aG;
  float Dsk = D_skip[d];
  float Wd = W_dt[d], bd = b_dt[d];

  float Ar2[16];
  #pragma unroll
  for (int n = 0; n < 16; n += 4) {
    f32x4 al = *(const f32x4*)(A_log + (size_t)d * DST + n0 + n);
    #pragma unroll
    for (int j = 0; j < 4; ++j) Ar2[n + j] = -__expf(al[j]) * 1.44269504f;
  }

  float h[16];
  size_t ob = (((size_t)c * NB + b) * DI + d) * DST + n0;
  #pragma unroll
  for (int n = 0; n < 16; n += 4) {
    f32x4 hv = *(const f32x4*)(PH + ob + n);
    #pragma unroll
    for (int j = 0; j < 4; ++j) h[n + j] = hv[j];
  }

  bf16* yc = yb + ((size_t)b * LSEQ + c * LC) * DI + d;

  __syncthreads();

  #pragma unroll 2
  for (int t = 0; t < LC; ++t) {
    float dtraw = Ds[t];
    float u = (float)Us[t][di];
    float s = fmaf(dtraw, Wd, bd);
    float dt = (s > 15.f) ? s : __logf(1.f + __expf(s));  // softplus
    float dtu = dt * u;
    float p0 = 0.f, p1 = 0.f, p2 = 0.f, p3 = 0.f;
    #pragma unroll
    for (int n4 = 0; n4 < 4; ++n4) {
      f32x4 Bq = *(const f32x4*)&BCs[t][n0 + n4 * 4];
      f32x4 Cq = *(const f32x4*)&BCs[t][32 + n0 + n4 * 4];
      #pragma unroll
      for (int j = 0; j < 4; ++j) {
        int n = n4 * 4 + j;
        float t1  = dt * Ar2[n];
        float ex  = exp2_(t1);
        float den = fmaf(t1, -0.34657359f, 1.000001f);
        float Ad  = fmaf(aG, ex, omA * __builtin_amdgcn_rcpf(den));
        h[n] = fmaf(Ad, h[n], dtu * Bq[j]);
        if (j == 0)      p0 = fmaf(Cq[j], h[n], p0);
        else if (j == 1) p1 = fmaf(Cq[j], h[n], p1);
        else if (j == 2) p2 = fmaf(Cq[j], h[n], p2);
        else             p3 = fmaf(Cq[j], h[n], p3);
      }
    }
    float part = (p0 + p1) + (p2 + p3);
    part += __shfl_xor(part, 32);   // combine the two 16-state halves
    if (nh == 0) {
      float g = (float)Gs[t][di];
      float y = fmaf(Dsk, u, part) * g;
      yc[(size_t)t * DI] = (bf16)y;
    }
  }
}

// ---------------- launch ----------------
extern "C" void kernel_launch(void* const* d_in, const int* in_sizes, int n_in,
                              void* d_out, int out_size, void* d_ws, size_t ws_size,
                              hipStream_t stream) {
  const float* x      = (const float*)d_in[0];
  const float* W_in   = (const float*)d_in[1];
  const float* conv_w = (const float*)d_in[2];
  const float* conv_b = (const float*)d_in[3];
  const float* A_log  = (const float*)d_in[4];
  const float* D_skip = (const float*)d_in[5];
  const float* W_xprj = (const float*)d_in[6];
  const float* W_dt   = (const float*)d_in[7];
  const float* b_dt   = (const float*)d_in[8];
  const float* alpha  = (const float*)d_in[9];
  const float* W_out  = (const float*)d_in[10];

  char* ws = (char*)d_ws;
  // Layout (within proven 141,033,472 B):
  bf16*  xzb   = (bf16*) (ws + 0);             // (4096,4096) bf16: 33,554,432
  bf16*  xconv = (bf16*) (ws + 67108864);      // (4096,2048) bf16: 16,777,216
  float* proj  = (float*)(ws + 83886080);      // (4096,128)  f32:   2,097,152
  bf16*  woutb = (bf16*) (ws + 85983232);      // (1024,2048) bf16:  4,194,304
  bf16*  wxpb  = (bf16*) (ws + 90177536);      // (128,2048)  bf16:    524,288
  bf16*  yb    = (bf16*) (ws + 90701824);      // (4096,2048) bf16: 16,777,216
  unsigned int* PH = (unsigned int*)(ws + 107479040);  // NC*NB*DI*DST u32: 33,554,432
  // overlays of the PH region (all dead before phase1 writes PH):
  bf16*  xb    = (bf16*) (ws + 107479040);     // (4096,1024) bf16: 8,388,608 (dead after GEMM1)
  bf16*  winb  = (bf16*) (ws + 115867648);     // (4096,1024) bf16: 8,388,608 (dead after GEMM1)
  float* projp = (float*)(ws + 107479040);     // 8x(4096,128) f32: 16,777,216 (dead after reduce)
  // after phase3, PH is dead again -> GEMM3 partials (2x4096x1024 f32 = 33.5 MB)
  float* outp  = (float*)(ws + 107479040);

  float* out = (float*)d_out;  // (4096, 1024) f32

  // merged casts + pad/permute
  prep_kernel<<<10496, 256, 0, stream>>>(x, W_in, W_out, W_xprj,
                                         xb, winb, woutb, wxpb);

  // xz = x @ W_in.T   (M=4096, N=4096, K=1024) -> bf16
  gemm_lds<bf16><<<dim3(32, 32, 1), 256, 0, stream>>>(xb, winb, xzb,
                                                      BL, 2 * DI, DM, 1);

  // x_conv = silu(conv1d(x_in))  (bf16 in/out)
  conv_silu_kernel<<<8192, 256, 0, stream>>>(xzb, xconv, conv_w, conv_b);

  // proj partials = x_conv @ W_xproj.T, K split 8-way; then reduce
  gemm_lds<float><<<dim3(1, 32, 8), 256, 0, stream>>>(xconv, wxpb, projp,
                                                      BL, 128, DI, 8);
  reduce_proj_kernel<<<512, 256, 0, stream>>>(projp, proj);

  // chunked scan (d-major, 2-way n-split, fully LDS-staged operands)
  scan_phase1<<<dim3(DI / 128, NB, NC - 1), 256, 0, stream>>>(proj, xconv,
                                                              A_log, W_dt,
                                                              b_dt, alpha, PH);
  scan_phase2<<<512, 256, 0, stream>>>(PH);
  scan_phase3<<<dim3(DI / 128, NB, NC), 256, 0, stream>>>(proj, xconv, xzb,
                                                          A_log, D_skip, W_dt,
                                                          b_dt, alpha,
                                                          (const float*)PH, yb);

  // out = y @ W_out.T (M=4096, N=1024, K=2048), K split 2-way into dead PH
  gemm_lds<float><<<dim3(8, 32, 2), 256, 0, stream>>>(yb, woutb, outp,
                                                      BL, DM, DI, 2);
  reduce_out_kernel<<<4096, 256, 0, stream>>>(outp, out);
}